// Round 12
// baseline (402.956 us; speedup 1.0000x reference)
//
#include <hip/hip_runtime.h>
#include <hip/hip_bf16.h>
#include <math.h>

#define B_N     4
#define L_N     2048
#define DMODEL  1024
#define DSTATE  128
#define DCONV   4
#define HEADDIM 64
#define CHUNK   256
#define DINNER  2048
#define NHEADS  32
#define CONVDIM 2304
#define DINPROJ 4384
#define NCHUNK  8
#define BL      (B_N*L_N)

typedef unsigned short ushort_t;
typedef unsigned int   uint_t;

typedef __attribute__((ext_vector_type(8))) short bf16x8;
typedef __attribute__((ext_vector_type(4))) float f32x4;

__device__ __forceinline__ float bfbits2f(ushort_t u){
    union { uint_t i; float f; } v; v.i = ((uint_t)u) << 16; return v.f;
}
__device__ __forceinline__ ushort_t f2bf(float f){
    union { float f; uint_t i; } v; v.f = f;
    uint_t r = v.i + 0x7FFF + ((v.i >> 16) & 1);
    return (ushort_t)(r >> 16);
}
__device__ __forceinline__ void gload_lds16(const void* g, void* l){
    __builtin_amdgcn_global_load_lds(
        (const __attribute__((address_space(1))) unsigned int*)g,
        (__attribute__((address_space(3))) unsigned int*)l, 16, 0, 0);
}

#define FENCE()  asm volatile("" ::: "memory")
#define WAITV8() asm volatile("s_waitcnt vmcnt(8)" ::: "memory")
#define WAITV4() asm volatile("s_waitcnt vmcnt(4)" ::: "memory")
#define WAITV0() asm volatile("s_waitcnt vmcnt(0)" ::: "memory")
#define BARRIER() { FENCE(); __builtin_amdgcn_s_barrier(); FENCE(); }

// ---------------------------------------------------------------------------
// K0: f32 -> bf16 convert (8 elems/thread)
// ---------------------------------------------------------------------------
__global__ __launch_bounds__(256) void cvt_bf16(
    const float* __restrict__ in, ushort_t* __restrict__ out, int n8)
{
    int i = blockIdx.x*256 + threadIdx.x;
    if (i >= n8) return;
    const float4* p = (const float4*)(in + (size_t)i*8);
    float4 a = p[0], b = p[1];
    ushort_t o[8] = { f2bf(a.x), f2bf(a.y), f2bf(a.z), f2bf(a.w),
                      f2bf(b.x), f2bf(b.y), f2bf(b.z), f2bf(b.w) };
    *(uint4*)(out + (size_t)i*8) = *(const uint4*)o;
}

// ---------------------------------------------------------------------------
// K0b: transpose conv weights: wT[k][c] = cw[c][k]
// ---------------------------------------------------------------------------
__global__ __launch_bounds__(256) void cvt_wT(
    const float* __restrict__ cw, float* __restrict__ wT)
{
    int c = blockIdx.x*256 + threadIdx.x;
    if (c >= CONVDIM) return;
    float4 v = *(const float4*)&cw[c*DCONV];
    wT[0*CONVDIM + c] = v.x;
    wT[1*CONVDIM + c] = v.y;
    wT[2*CONVDIM + c] = v.z;
    wT[3*CONVDIM + c] = v.w;
}

// ---------------------------------------------------------------------------
// K1-IN: in-proj 256x256/BK=64 pipelined GEMM (4-phase, counted vmcnt, T2 swz)
// C = A @ B^T; A [8192][1024] bf16, B [DINPROJ][1024] bf16 (rows >=DINPROJ clamped)
// Split epilogue: z / xbc_raw / softplus-dt.
// LDS: [2 buf][2 khalf][128 pr][128 B] per operand = 128 KiB, 1 block/CU.
// Swizzle: logical 16B-block lb4 stored at phys blk = lb4 ^ (pr&3) (both sides).
// ---------------------------------------------------------------------------
__global__ __launch_bounds__(512) void gemm_inproj_8ph(
    const ushort_t* __restrict__ A, const ushort_t* __restrict__ B,
    ushort_t* __restrict__ z, ushort_t* __restrict__ xbc,
    const float* __restrict__ dt_bias, float* __restrict__ dtp)
{
    constexpr int KD = DMODEL;          // 1024
    constexpr int NT = KD/64;           // 16 K-tiles
    constexpr int NTILES = 18;          // N padded to 4608
    __shared__ __align__(16) ushort_t Alds[2][2][128*64];   // 64 KB
    __shared__ __align__(16) ushort_t Blds[2][2][128*64];   // 64 KB

    int nwg = gridDim.x, cpx = nwg >> 3, lin = blockIdx.x;
    int work = (lin & 7)*cpx + (lin >> 3);
    int mtile = work / NTILES, ntile = work % NTILES;
    int m0 = mtile*256, n0 = ntile*256;

    int t = threadIdx.x;
    int l = t & 63, w = t >> 6;         // 8 waves
    int wm = w >> 2, wn = w & 3;        // 2M x 4N
    int l15 = l & 15, l4 = l >> 4;

    // staging lane geometry (region-independent parts)
    int s_pr8  = l >> 3;                // pr offset within region
    int s_rlow = (l >> 2) & 1;
    int s_lb4  = (l & 3) ^ ((l >> 3) & 3);

    f32x4 acc[8][4];
    #pragma unroll
    for (int m=0;m<8;m++){
        #pragma unroll
        for (int n=0;n<4;n++) acc[m][n] = (f32x4){0.f,0.f,0.f,0.f};
    }

    auto stageA = [&](int buf,int kh,int kt,int j){
        int region = w*2 + j;
        int pr = region*8 + s_pr8;
        int r  = 2*pr + s_rlow;
        const ushort_t* src = A + (size_t)(m0 + r)*KD + kt*64 + kh*32 + s_lb4*8;
        gload_lds16(src, &Alds[buf][kh][region*512 + l*8]);
    };
    auto stageB = [&](int buf,int kh,int kt,int j){
        int region = w*2 + j;
        int pr = region*8 + s_pr8;
        int r  = 2*pr + s_rlow;
        int gr = n0 + r; gr = (gr < DINPROJ) ? gr : (DINPROJ-1);
        const ushort_t* src = B + (size_t)gr*KD + kt*64 + kh*32 + s_lb4*8;
        gload_lds16(src, &Blds[buf][kh][region*512 + l*8]);
    };
    auto Afrag = [&](int buf,int kh,int m)->bf16x8{
        int r = wm*128 + m*16 + l15;
        int pr = r >> 1;
        return *(const bf16x8*)&Alds[buf][kh][pr*64 + (r&1)*32 + (l4 ^ (pr&3))*8];
    };
    auto Bfrag = [&](int buf,int kh,int n)->bf16x8{
        int r = wn*64 + n*16 + l15;
        int pr = r >> 1;
        return *(const bf16x8*)&Blds[buf][kh][pr*64 + (r&1)*32 + (l4 ^ (pr&3))*8];
    };

    // prologue: kh0(0), kh1(0), kh0(1)  -> 12 loads/thread in flight
    stageA(0,0,0,0); stageA(0,0,0,1); stageB(0,0,0,0); stageB(0,0,0,1);
    stageA(0,1,0,0); stageA(0,1,0,1); stageB(0,1,0,0); stageB(0,1,0,1);
    stageA(1,0,1,0); stageA(1,0,1,1); stageB(1,0,1,0); stageB(1,0,1,1);

    for (int kt = 0; kt < NT-1; ++kt){
        int buf = kt & 1, bufo = buf ^ 1;
        bool s2 = (kt + 2 < NT);
        // ---- ph0: kh0, m-rows 0..3
        WAITV8(); BARRIER();
        {
            bf16x8 b0 = Bfrag(buf,0,0), b1 = Bfrag(buf,0,1), b2 = Bfrag(buf,0,2), b3 = Bfrag(buf,0,3);
            bf16x8 a0 = Afrag(buf,0,0), a1 = Afrag(buf,0,1), a2 = Afrag(buf,0,2), a3 = Afrag(buf,0,3);
            stageA(bufo,1,kt+1,0); stageA(bufo,1,kt+1,1);
            __builtin_amdgcn_s_setprio(1);
            acc[0][0]=__builtin_amdgcn_mfma_f32_16x16x32_bf16(a0,b0,acc[0][0],0,0,0);
            acc[0][1]=__builtin_amdgcn_mfma_f32_16x16x32_bf16(a0,b1,acc[0][1],0,0,0);
            acc[0][2]=__builtin_amdgcn_mfma_f32_16x16x32_bf16(a0,b2,acc[0][2],0,0,0);
            acc[0][3]=__builtin_amdgcn_mfma_f32_16x16x32_bf16(a0,b3,acc[0][3],0,0,0);
            acc[1][0]=__builtin_amdgcn_mfma_f32_16x16x32_bf16(a1,b0,acc[1][0],0,0,0);
            acc[1][1]=__builtin_amdgcn_mfma_f32_16x16x32_bf16(a1,b1,acc[1][1],0,0,0);
            acc[1][2]=__builtin_amdgcn_mfma_f32_16x16x32_bf16(a1,b2,acc[1][2],0,0,0);
            acc[1][3]=__builtin_amdgcn_mfma_f32_16x16x32_bf16(a1,b3,acc[1][3],0,0,0);
            acc[2][0]=__builtin_amdgcn_mfma_f32_16x16x32_bf16(a2,b0,acc[2][0],0,0,0);
            acc[2][1]=__builtin_amdgcn_mfma_f32_16x16x32_bf16(a2,b1,acc[2][1],0,0,0);
            acc[2][2]=__builtin_amdgcn_mfma_f32_16x16x32_bf16(a2,b2,acc[2][2],0,0,0);
            acc[2][3]=__builtin_amdgcn_mfma_f32_16x16x32_bf16(a2,b3,acc[2][3],0,0,0);
            acc[3][0]=__builtin_amdgcn_mfma_f32_16x16x32_bf16(a3,b0,acc[3][0],0,0,0);
            acc[3][1]=__builtin_amdgcn_mfma_f32_16x16x32_bf16(a3,b1,acc[3][1],0,0,0);
            acc[3][2]=__builtin_amdgcn_mfma_f32_16x16x32_bf16(a3,b2,acc[3][2],0,0,0);
            acc[3][3]=__builtin_amdgcn_mfma_f32_16x16x32_bf16(a3,b3,acc[3][3],0,0,0);
            __builtin_amdgcn_s_setprio(0);
            // ---- ph1: kh0, m-rows 4..7
            bf16x8 a4 = Afrag(buf,0,4), a5 = Afrag(buf,0,5), a6 = Afrag(buf,0,6), a7 = Afrag(buf,0,7);
            stageB(bufo,1,kt+1,0); stageB(bufo,1,kt+1,1);
            __builtin_amdgcn_s_setprio(1);
            acc[4][0]=__builtin_amdgcn_mfma_f32_16x16x32_bf16(a4,b0,acc[4][0],0,0,0);
            acc[4][1]=__builtin_amdgcn_mfma_f32_16x16x32_bf16(a4,b1,acc[4][1],0,0,0);
            acc[4][2]=__builtin_amdgcn_mfma_f32_16x16x32_bf16(a4,b2,acc[4][2],0,0,0);
            acc[4][3]=__builtin_amdgcn_mfma_f32_16x16x32_bf16(a4,b3,acc[4][3],0,0,0);
            acc[5][0]=__builtin_amdgcn_mfma_f32_16x16x32_bf16(a5,b0,acc[5][0],0,0,0);
            acc[5][1]=__builtin_amdgcn_mfma_f32_16x16x32_bf16(a5,b1,acc[5][1],0,0,0);
            acc[5][2]=__builtin_amdgcn_mfma_f32_16x16x32_bf16(a5,b2,acc[5][2],0,0,0);
            acc[5][3]=__builtin_amdgcn_mfma_f32_16x16x32_bf16(a5,b3,acc[5][3],0,0,0);
            acc[6][0]=__builtin_amdgcn_mfma_f32_16x16x32_bf16(a6,b0,acc[6][0],0,0,0);
            acc[6][1]=__builtin_amdgcn_mfma_f32_16x16x32_bf16(a6,b1,acc[6][1],0,0,0);
            acc[6][2]=__builtin_amdgcn_mfma_f32_16x16x32_bf16(a6,b2,acc[6][2],0,0,0);
            acc[6][3]=__builtin_amdgcn_mfma_f32_16x16x32_bf16(a6,b3,acc[6][3],0,0,0);
            acc[7][0]=__builtin_amdgcn_mfma_f32_16x16x32_bf16(a7,b0,acc[7][0],0,0,0);
            acc[7][1]=__builtin_amdgcn_mfma_f32_16x16x32_bf16(a7,b1,acc[7][1],0,0,0);
            acc[7][2]=__builtin_amdgcn_mfma_f32_16x16x32_bf16(a7,b2,acc[7][2],0,0,0);
            acc[7][3]=__builtin_amdgcn_mfma_f32_16x16x32_bf16(a7,b3,acc[7][3],0,0,0);
            __builtin_amdgcn_s_setprio(0);
        }
        // ---- ph2: kh1, m-rows 0..3
        WAITV8(); BARRIER();
        {
            bf16x8 b0 = Bfrag(buf,1,0), b1 = Bfrag(buf,1,1), b2 = Bfrag(buf,1,2), b3 = Bfrag(buf,1,3);
            bf16x8 a0 = Afrag(buf,1,0), a1 = Afrag(buf,1,1), a2 = Afrag(buf,1,2), a3 = Afrag(buf,1,3);
            if (s2){ stageA(buf,0,kt+2,0); stageA(buf,0,kt+2,1); }
            __builtin_amdgcn_s_setprio(1);
            acc[0][0]=__builtin_amdgcn_mfma_f32_16x16x32_bf16(a0,b0,acc[0][0],0,0,0);
            acc[0][1]=__builtin_amdgcn_mfma_f32_16x16x32_bf16(a0,b1,acc[0][1],0,0,0);
            acc[0][2]=__builtin_amdgcn_mfma_f32_16x16x32_bf16(a0,b2,acc[0][2],0,0,0);
            acc[0][3]=__builtin_amdgcn_mfma_f32_16x16x32_bf16(a0,b3,acc[0][3],0,0,0);
            acc[1][0]=__builtin_amdgcn_mfma_f32_16x16x32_bf16(a1,b0,acc[1][0],0,0,0);
            acc[1][1]=__builtin_amdgcn_mfma_f32_16x16x32_bf16(a1,b1,acc[1][1],0,0,0);
            acc[1][2]=__builtin_amdgcn_mfma_f32_16x16x32_bf16(a1,b2,acc[1][2],0,0,0);
            acc[1][3]=__builtin_amdgcn_mfma_f32_16x16x32_bf16(a1,b3,acc[1][3],0,0,0);
            acc[2][0]=__builtin_amdgcn_mfma_f32_16x16x32_bf16(a2,b0,acc[2][0],0,0,0);
            acc[2][1]=__builtin_amdgcn_mfma_f32_16x16x32_bf16(a2,b1,acc[2][1],0,0,0);
            acc[2][2]=__builtin_amdgcn_mfma_f32_16x16x32_bf16(a2,b2,acc[2][2],0,0,0);
            acc[2][3]=__builtin_amdgcn_mfma_f32_16x16x32_bf16(a2,b3,acc[2][3],0,0,0);
            acc[3][0]=__builtin_amdgcn_mfma_f32_16x16x32_bf16(a3,b0,acc[3][0],0,0,0);
            acc[3][1]=__builtin_amdgcn_mfma_f32_16x16x32_bf16(a3,b1,acc[3][1],0,0,0);
            acc[3][2]=__builtin_amdgcn_mfma_f32_16x16x32_bf16(a3,b2,acc[3][2],0,0,0);
            acc[3][3]=__builtin_amdgcn_mfma_f32_16x16x32_bf16(a3,b3,acc[3][3],0,0,0);
            __builtin_amdgcn_s_setprio(0);
            // ---- ph3: kh1, m-rows 4..7
            bf16x8 a4 = Afrag(buf,1,4), a5 = Afrag(buf,1,5), a6 = Afrag(buf,1,6), a7 = Afrag(buf,1,7);
            if (s2){ stageB(buf,0,kt+2,0); stageB(buf,0,kt+2,1); }
            __builtin_amdgcn_s_setprio(1);
            acc[4][0]=__builtin_amdgcn_mfma_f32_16x16x32_bf16(a4,b0,acc[4][0],0,0,0);
            acc[4][1]=__builtin_amdgcn_mfma_f32_16x16x32_bf16(a4,b1,acc[4][1],0,0,0);
            acc[4][2]=__builtin_amdgcn_mfma_f32_16x16x32_bf16(a4,b2,acc[4][2],0,0,0);
            acc[4][3]=__builtin_amdgcn_mfma_f32_16x16x32_bf16(a4,b3,acc[4][3],0,0,0);
            acc[5][0]=__builtin_amdgcn_mfma_f32_16x16x32_bf16(a5,b0,acc[5][0],0,0,0);
            acc[5][1]=__builtin_amdgcn_mfma_f32_16x16x32_bf16(a5,b1,acc[5][1],0,0,0);
            acc[5][2]=__builtin_amdgcn_mfma_f32_16x16x32_bf16(a5,b2,acc[5][2],0,0,0);
            acc[5][3]=__builtin_amdgcn_mfma_f32_16x16x32_bf16(a5,b3,acc[5][3],0,0,0);
            acc[6][0]=__builtin_amdgcn_mfma_f32_16x16x32_bf16(a6,b0,acc[6][0],0,0,0);
            acc[6][1]=__builtin_amdgcn_mfma_f32_16x16x32_bf16(a6,b1,acc[6][1],0,0,0);
            acc[6][2]=__builtin_amdgcn_mfma_f32_16x16x32_bf16(a6,b2,acc[6][2],0,0,0);
            acc[6][3]=__builtin_amdgcn_mfma_f32_16x16x32_bf16(a6,b3,acc[6][3],0,0,0);
            acc[7][0]=__builtin_amdgcn_mfma_f32_16x16x32_bf16(a7,b0,acc[7][0],0,0,0);
            acc[7][1]=__builtin_amdgcn_mfma_f32_16x16x32_bf16(a7,b1,acc[7][1],0,0,0);
            acc[7][2]=__builtin_amdgcn_mfma_f32_16x16x32_bf16(a7,b2,acc[7][2],0,0,0);
            acc[7][3]=__builtin_amdgcn_mfma_f32_16x16x32_bf16(a7,b3,acc[7][3],0,0,0);
            __builtin_amdgcn_s_setprio(0);
        }
    }
    // ---- peeled last K-tile (kt = NT-1): no staging, tightened waits
    {
        int buf = (NT-1) & 1;
        WAITV4(); BARRIER();
        #pragma unroll
        for (int kh=0; kh<2; kh++){
            if (kh == 1){ WAITV0(); BARRIER(); }
            bf16x8 b0 = Bfrag(buf,kh,0), b1 = Bfrag(buf,kh,1), b2 = Bfrag(buf,kh,2), b3 = Bfrag(buf,kh,3);
            #pragma unroll
            for (int m=0;m<8;m++){
                bf16x8 a = Afrag(buf,kh,m);
                acc[m][0]=__builtin_amdgcn_mfma_f32_16x16x32_bf16(a,b0,acc[m][0],0,0,0);
                acc[m][1]=__builtin_amdgcn_mfma_f32_16x16x32_bf16(a,b1,acc[m][1],0,0,0);
                acc[m][2]=__builtin_amdgcn_mfma_f32_16x16x32_bf16(a,b2,acc[m][2],0,0,0);
                acc[m][3]=__builtin_amdgcn_mfma_f32_16x16x32_bf16(a,b3,acc[m][3],0,0,0);
            }
        }
    }

    // ---- split epilogue
    #pragma unroll
    for (int m=0;m<8;m++){
        int rbase = m0 + wm*128 + m*16 + l4*4;
        #pragma unroll
        for (int n=0;n<4;n++){
            int gcol = n0 + wn*64 + n*16 + l15;
            f32x4 v = acc[m][n];
            #pragma unroll
            for (int q=0;q<4;q++){
                int row = rbase + q;
                if (gcol < DINNER) {
                    z[(size_t)row*DINNER + gcol] = f2bf(v[q]);
                } else if (gcol < DINNER + CONVDIM) {
                    xbc[(size_t)row*CONVDIM + (gcol - DINNER)] = f2bf(v[q]);
                } else if (gcol < DINPROJ) {
                    int hh = gcol - (DINNER + CONVDIM);
                    float x = v[q] + dt_bias[hh];
                    float sp = (x > 15.f) ? x : log1pf(__expf(x));
                    int bb = row >> 11, ll = row & (L_N-1);
                    dtp[((size_t)bb*NHEADS + hh)*L_N + ll] = sp;
                }
            }
        }
    }
}

// ---------------------------------------------------------------------------
// K1-OUT: proven 2-phase 128x128 GEMM (R7 config) for out-proj
// ---------------------------------------------------------------------------
template<int KDIM, int NTILES>
__global__ __launch_bounds__(256) void gemm_bt_mfma(
    const ushort_t* __restrict__ A, const ushort_t* __restrict__ B,
    float* __restrict__ outf)
{
    __shared__ __align__(16) ushort_t Asl[2][128*32];
    __shared__ __align__(16) ushort_t Bsl[2][128*32];

    int nwg = gridDim.x, cpx = nwg >> 3, lin = blockIdx.x;
    int work = (lin & 7)*cpx + (lin >> 3);
    int mtile = work / NTILES, ntile = work % NTILES;
    int m0 = mtile*128, n0 = ntile*128;

    int t = threadIdx.x;
    int l = t & 63, w = t >> 6;
    int wr = w >> 1, wc = w & 1;
    int lr16 = l & 15, kb = l >> 4;
    int srow = t >> 2, skc = (t & 3)*8;

    f32x4 acc[4][4];
    #pragma unroll
    for (int m=0;m<4;m++){
        #pragma unroll
        for (int n=0;n<4;n++) acc[m][n] = (f32x4){0.f,0.f,0.f,0.f};
    }

    auto stage = [&](int buf, int k0){
        gload_lds16(A + (size_t)(m0+srow)*KDIM + k0 + skc,    &Asl[buf][t*8]);
        gload_lds16(A + (size_t)(m0+64+srow)*KDIM + k0 + skc, &Asl[buf][2048 + t*8]);
        gload_lds16(B + (size_t)(n0+srow)*KDIM + k0 + skc,    &Bsl[buf][t*8]);
        gload_lds16(B + (size_t)(n0+64+srow)*KDIM + k0 + skc, &Bsl[buf][2048 + t*8]);
    };
    auto compute = [&](int cur){
        bf16x8 af[4], bfr[4];
        #pragma unroll
        for (int m=0;m<4;m++) af[m]  = *(const bf16x8*)&Asl[cur][(wr*64+m*16+lr16)*32 + kb*8];
        #pragma unroll
        for (int n=0;n<4;n++) bfr[n] = *(const bf16x8*)&Bsl[cur][(wc*64+n*16+lr16)*32 + kb*8];
        __builtin_amdgcn_s_setprio(1);
        #pragma unroll
        for (int m=0;m<4;m++){
            #pragma unroll
            for (int n=0;n<4;n++)
                acc[m][n] = __builtin_amdgcn_mfma_f32_16x16x32_bf16(af[m], bfr[n], acc[m][n], 0, 0, 0);
        }
        __builtin_amdgcn_s_setprio(0);
    };

    stage(0, 0);
    __syncthreads();
    int cur = 0;
    for (int k0=32; k0<KDIM; k0+=32){
        stage(cur^1, k0);
        compute(cur);
        __syncthreads();
        cur ^= 1;
    }
    compute(cur);

    #pragma unroll
    for (int m=0;m<4;m++){
        int rbase = m0 + wr*64 + m*16 + (l>>4)*4;
        #pragma unroll
        for (int n=0;n<4;n++){
            int gcol = n0 + wc*64 + n*16 + lr16;
            f32x4 v = acc[m][n];
            #pragma unroll
            for (int q=0;q<4;q++)
                outf[(size_t)(rbase+q)*DMODEL + gcol] = v[q];
        }
    }
}

// ---------------------------------------------------------------------------
// K2: causal depthwise conv1d (width 4) + bias + SiLU — bf16x8, wT[k][c]
// ---------------------------------------------------------------------------
__global__ __launch_bounds__(256) void conv_silu(
    const __hip_bfloat16* __restrict__ xraw,
    const float* __restrict__ wT, const float* __restrict__ cb,
    __hip_bfloat16* __restrict__ xout)
{
    int idx = blockIdx.x*256 + threadIdx.x;
    int c8 = (idx % (CONVDIM/8))*8;
    int ml = idx / (CONVDIM/8);
    int b  = ml >> 11, l = ml & (L_N-1);
    const ushort_t* xr = (const ushort_t*)xraw;
    float acc[8];
    {
        float4 b0 = *(const float4*)&cb[c8];
        float4 b1 = *(const float4*)&cb[c8+4];
        acc[0]=b0.x; acc[1]=b0.y; acc[2]=b0.z; acc[3]=b0.w;
        acc[4]=b1.x; acc[5]=b1.y; acc[6]=b1.z; acc[7]=b1.w;
    }
    #pragma unroll
    for (int k=0;k<DCONV;k++){
        int li = l - (DCONV-1) + k;
        if (li >= 0){
            bf16x8 v = *(const bf16x8*)&xr[((size_t)b*L_N + li)*CONVDIM + c8];
            float4 w0 = *(const float4*)&wT[k*CONVDIM + c8];
            float4 w1 = *(const float4*)&wT[k*CONVDIM + c8 + 4];
            float wv[8] = {w0.x,w0.y,w0.z,w0.w,w1.x,w1.y,w1.z,w1.w};
            #pragma unroll
            for (int e=0;e<8;e++)
                acc[e] += wv[e] * bfbits2f(((const ushort_t*)&v)[e]);
        }
    }
    ushort_t o[8];
    #pragma unroll
    for (int e=0;e<8;e++){
        float s = acc[e] / (1.f + __expf(-acc[e]));
        o[e] = f2bf(s);
    }
    *(uint4*)((ushort_t*)xout + (size_t)idx*8) = *(const uint4*)o;
}

// ---------------------------------------------------------------------------
// K3: dA = dt*A; inclusive cumsum within each chunk
// ---------------------------------------------------------------------------
__global__ __launch_bounds__(256) void dt_cumsum(
    const float* __restrict__ dtp, const float* __restrict__ A_log,
    float* __restrict__ dAcs)
{
    int blk = blockIdx.x;
    int c  = blk % NCHUNK;
    int bh = blk / NCHUNK;
    int h  = bh & (NHEADS-1);
    int t  = threadIdx.x;
    float A = -__expf(A_log[h]);
    __shared__ float sm[CHUNK];
    float v = dtp[(size_t)bh*L_N + c*CHUNK + t] * A;
    sm[t] = v;
    __syncthreads();
    for (int off=1; off<CHUNK; off<<=1){
        float add = (t >= off) ? sm[t-off] : 0.f;
        __syncthreads();
        sm[t] += add;
        __syncthreads();
    }
    dAcs[(size_t)bh*L_N + c*CHUNK + t] = sm[t];
}

// ---------------------------------------------------------------------------
// K4: S_T[bc][j][i] = sum_n B[j,n]*C[i,n]  (bf16), once per chunk
// ---------------------------------------------------------------------------
__global__ __launch_bounds__(256) void bc_scores_mfma(
    const __hip_bfloat16* __restrict__ xbc, ushort_t* __restrict__ S_T)
{
    __shared__ __align__(16) ushort_t Bs2[256*136];
    __shared__ __align__(16) ushort_t Cs2[256*136];
    int bc = blockIdx.x;
    int t = threadIdx.x;
    int l = t & 63, w = t >> 6;
    int l15 = l & 15, l4 = l >> 4;
    const ushort_t* xb = (const ushort_t*)xbc;
    const size_t rowbase = (size_t)bc*CHUNK*CONVDIM;

    #pragma unroll
    for (int ps=0; ps<16; ps++){
        int idx = ps*256 + t;
        int r = idx >> 4, ck = idx & 15;
        *(uint4*)&Bs2[r*136 + ck*8] =
            *(const uint4*)&xb[rowbase + (size_t)r*CONVDIM + DINNER + ck*8];
        *(uint4*)&Cs2[r*136 + ck*8] =
            *(const uint4*)&xb[rowbase + (size_t)r*CONVDIM + (DINNER+DSTATE) + ck*8];
    }
    __syncthreads();

    ushort_t* Sb = S_T + (size_t)bc*CHUNK*264;
    for (int if4 = w; if4 < 4; if4++){
        f32x4 acc[4][4];
        #pragma unroll
        for (int jf=0;jf<4;jf++){
            #pragma unroll
            for (int ir=0;ir<4;ir++) acc[jf][ir] = (f32x4){0.f,0.f,0.f,0.f};
        }
        #pragma unroll
        for (int k=0;k<4;k++){
            bf16x8 af[4], bfC[4];
            #pragma unroll
            for (int jf=0;jf<4;jf++)
                af[jf] = *(const bf16x8*)&Bs2[(w*64 + jf*16 + l15)*136 + k*32 + l4*8];
            #pragma unroll
            for (int ir=0;ir<4;ir++)
                bfC[ir] = *(const bf16x8*)&Cs2[(if4*64 + ir*16 + l15)*136 + k*32 + l4*8];
            #pragma unroll
            for (int jf=0;jf<4;jf++){
                #pragma unroll
                for (int ir=0;ir<4;ir++)
                    acc[jf][ir] = __builtin_amdgcn_mfma_f32_16x16x32_bf16(af[jf], bfC[ir], acc[jf][ir], 0, 0, 0);
            }
        }
        #pragma unroll
        for (int jf=0;jf<4;jf++){
            #pragma unroll
            for (int ir=0;ir<4;ir++){
                #pragma unroll
                for (int q=0;q<4;q++){
                    int j = w*64 + jf*16 + l4*4 + q;
                    int i = if4*64 + ir*16 + l15;
                    Sb[(size_t)j*264 + i] = f2bf(acc[jf][ir][q]);
                }
            }
        }
    }
}

// ---------------------------------------------------------------------------
// K6: states via MFMA, 4 heads per block
// ---------------------------------------------------------------------------
__device__ __forceinline__ int swz264(int row, int col){
    return row*264 + (col ^ (((row>>3)&7)<<3));
}

__global__ __launch_bounds__(256) void ssd_states_mfma(
    const __hip_bfloat16* __restrict__ xbc,
    const float* __restrict__ dtp, const float* __restrict__ dAcs,
    float* __restrict__ states)
{
    __shared__ __align__(16) ushort_t xdT[64*264];
    __shared__ __align__(16) ushort_t BT[128*264];
    __shared__ float coef_s[CHUNK];
    int bc = blockIdx.x, hg = blockIdx.y;
    int b = bc >> 3, c = bc & 7;
    int t = threadIdx.x;
    int l = t & 63, w = t >> 6;
    int l15 = l & 15, l4 = l >> 4;
    const ushort_t* xb = (const ushort_t*)xbc;
    const size_t rowbase = (size_t)bc*CHUNK*CONVDIM;

    #pragma unroll
    for (int ps=0; ps<16; ps++){
        int idx = ps*256 + t;
        int j = idx >> 4, n0 = (idx & 15)*8;
        bf16x8 v = *(const bf16x8*)&xb[rowbase + (size_t)j*CONVDIM + DINNER + n0];
        #pragma unroll
        for (int e=0;e<8;e++)
            BT[swz264(n0+e, j)] = ((const ushort_t*)&v)[e];
    }

    for (int hh=0; hh<4; hh++){
        int h = hg*4 + hh;
        size_t dbase = ((size_t)b*NHEADS + h)*L_N + c*CHUNK;
        float last = dAcs[dbase + CHUNK-1];
        float cf = __expf(last - dAcs[dbase + t]) * dtp[dbase + t];
        coef_s[t] = cf;
        __syncthreads();

        #pragma unroll
        for (int ps=0; ps<8; ps++){
            int idx = ps*256 + t;
            int j = idx >> 3, p0 = (idx & 7)*8;
            float cj = coef_s[j];
            bf16x8 v = *(const bf16x8*)&xb[rowbase + (size_t)j*CONVDIM + h*HEADDIM + p0];
            #pragma unroll
            for (int e=0;e<8;e++)
                xdT[swz264(p0+e, j)] = f2bf(cj * bfbits2f(((const ushort_t*)&v)[e]));
        }
        __syncthreads();

        f32x4 acc[4][2];
        #pragma unroll
        for (int pf=0;pf<4;pf++){
            #pragma unroll
            for (int nf=0;nf<2;nf++) acc[pf][nf] = (f32x4){0.f,0.f,0.f,0.f};
        }

        #pragma unroll
        for (int k=0;k<8;k++){
            bf16x8 af[4], bv[2];
            #pragma unroll
            for (int pf=0;pf<4;pf++)
                af[pf] = *(const bf16x8*)&xdT[swz264(pf*16 + l15, k*32 + l4*8)];
            #pragma unroll
            for (int nf=0;nf<2;nf++)
                bv[nf] = *(const bf16x8*)&BT[swz264(w*32 + nf*16 + l15, k*32 + l4*8)];
            #pragma unroll
            for (int pf=0;pf<4;pf++){
                #pragma unroll
                for (int nf=0;nf<2;nf++)
                    acc[pf][nf] = __builtin_amdgcn_mfma_f32_16x16x32_bf16(af[pf], bv[nf], acc[pf][nf], 0, 0, 0);
            }
        }

        float* sb = states + (size_t)(bc*NHEADS + h)*HEADDIM*DSTATE;
        #pragma unroll
        for (int pf=0;pf<4;pf++){
            #pragma unroll
            for (int nf=0;nf<2;nf++){
                #pragma unroll
                for (int q=0;q<4;q++){
                    int p = pf*16 + l4*4 + q;
                    int n = w*32 + nf*16 + l15;
                    sb[(size_t)p*DSTATE + n] = acc[pf][nf][q];
                }
            }
        }
    }
}

// ---------------------------------------------------------------------------
// K7: inter-chunk scan
// ---------------------------------------------------------------------------
__global__ __launch_bounds__(256) void scan_states(
    float* __restrict__ states, const float* __restrict__ dAcs)
{
    int idx = blockIdx.x*256 + threadIdx.x;
    int n  = idx & 127;
    int p  = (idx >> 7) & 63;
    int bh = idx >> 13;
    int b  = bh >> 5, h = bh & 31;
    float carry = 0.f;
    for (int c=0;c<NCHUNK;c++){
        size_t off = (((size_t)((b*NCHUNK + c)*NHEADS + h))*HEADDIM + p)*DSTATE + n;
        float s = states[off];
        states[off] = carry;
        float cd = __expf(dAcs[((size_t)b*NHEADS + h)*L_N + c*CHUNK + (CHUNK-1)]);
        carry = carry * cd + s;
    }
}

// ---------------------------------------------------------------------------
// K5: fused MFMA SSD -> bf16 yh
// ---------------------------------------------------------------------------
__global__ __launch_bounds__(256) void ssd_mfma(
    const __hip_bfloat16* __restrict__ xbc,
    const float* __restrict__ dtp, const float* __restrict__ dAcs,
    const float* __restrict__ states, const ushort_t* __restrict__ S_T,
    const float* __restrict__ D_param, ushort_t* __restrict__ yh)
{
    __shared__ __align__(16) ushort_t Ws[256*72];
    __shared__ __align__(16) ushort_t xdT[64*264];
    __shared__ float da_s[CHUNK];
    __shared__ float dt_s[CHUNK];

    int bc = blockIdx.x, h = blockIdx.y;
    int b = bc >> 3, c = bc & 7;
    int t = threadIdx.x;
    int l = t & 63, w = t >> 6;
    int l15 = l & 15, l4 = l >> 4;

    const ushort_t* xb = (const ushort_t*)xbc;
    const size_t rowbase = (size_t)bc*CHUNK*CONVDIM;

    da_s[t] = dAcs[((size_t)b*NHEADS + h)*L_N + c*CHUNK + t];
    dt_s[t] = dtp[((size_t)b*NHEADS + h)*L_N + c*CHUNK + t];

    #pragma unroll
    for (int ps=0; ps<8; ps++){
        int idx = ps*256 + t;
        int j = idx >> 3, p0 = (idx & 7)*8;
        bf16x8 v = *(const bf16x8*)&xb[rowbase + (size_t)j*CONVDIM + h*HEADDIM + p0];
        #pragma unroll
        for (int e=0;e<8;e++) xdT[(p0+e)*264 + j] = ((const ushort_t*)&v)[e];
    }
    __syncthreads();

    f32x4 yacc[4][4];
    #pragma unroll
    for (int m=0;m<4;m++){
        #pragma unroll
        for (int np=0;np<4;np++) yacc[m][np] = (f32x4){0.f,0.f,0.f,0.f};
    }

    const ushort_t* cbase = xb + rowbase + (size_t)l15*CONVDIM + (DINNER+DSTATE) + l4*8;
    const float*    pbase = states + (size_t)(bc*NHEADS + h)*HEADDIM*DSTATE
                                   + (size_t)l15*DSTATE + l4*8;
    #pragma unroll
    for (int k=0;k<4;k++){
        bf16x8 bfk[4];
        #pragma unroll
        for (int np=0;np<4;np++){
            const float* pr = pbase + (size_t)(np*16)*DSTATE + k*32;
            float4 a = *(const float4*)pr;
            float4 bq = *(const float4*)(pr + 4);
            bf16x8 r;
            r[0]=(short)f2bf(a.x);  r[1]=(short)f2bf(a.y);
            r[2]=(short)f2bf(a.z);  r[3]=(short)f2bf(a.w);
            r[4]=(short)f2bf(bq.x); r[5]=(short)f2bf(bq.y);
            r[6]=(short)f2bf(bq.z); r[7]=(short)f2bf(bq.w);
            bfk[np] = r;
        }
        #pragma unroll
        for (int m=0;m<4;m++){
            int i0 = (m*4 + w)*16;
            bf16x8 af = *(const bf16x8*)(cbase + (size_t)i0*CONVDIM + k*32);
            #pragma unroll
            for (int np=0;np<4;np++)
                yacc[m][np] = __builtin_amdgcn_mfma_f32_16x16x32_bf16(af, bfk[np], yacc[m][np], 0, 0, 0);
        }
    }
    #pragma unroll
    for (int m=0;m<4;m++){
        int i0 = (m*4 + w)*16;
        #pragma unroll
        for (int q=0;q<4;q++){
            float e = __expf(da_s[i0 + l4*4 + q]);
            #pragma unroll
            for (int np=0;np<4;np++) yacc[m][np][q] *= e;
        }
    }

    const ushort_t* Sb = S_T + (size_t)bc*CHUNK*264;
    for (int jp=0; jp<4; jp++){
        bf16x8 bfx[4][2];
        #pragma unroll
        for (int np=0;np<4;np++){
            #pragma unroll
            for (int ks=0;ks<2;ks++)
                bfx[np][ks] = *(const bf16x8*)&xdT[(np*16 + l15)*264 + jp*64 + ks*32 + l4*8];
        }

        #pragma unroll
        for (int m=0;m<4;m++){
            int i0 = (m*4 + w)*16;
            int imax = i0 + 15;
            int kmaxY = (jp*64 <= imax ? 1 : 0) + (jp*64+32 <= imax ? 1 : 0);
            if (kmaxY == 0) continue;
            int nmax = 2*kmaxY;

            float dai[4];
            #pragma unroll
            for (int q=0;q<4;q++) dai[q] = da_s[i0 + l4*4 + q];
            #pragma unroll
            for (int n=0;n<4;n++){
                if (n < nmax){
                    int jcol = jp*64 + n*16 + l15;
                    float daj = da_s[jcol], dtj = dt_s[jcol];
                    ushort_t sv[4];
                    *(uint2*)sv = *(const uint2*)&Sb[(size_t)jcol*264 + i0 + l4*4];
                    #pragma unroll
                    for (int q=0;q<4;q++){
                        int i = i0 + l4*4 + q;
                        float wv = 0.f;
                        if (jcol <= i) wv = __expf(dai[q] - daj) * dtj * bfbits2f(sv[q]);
                        Ws[i*72 + n*16 + l15] = f2bf(wv);
                    }
                }
            }
            #pragma unroll
            for (int ks=0;ks<2;ks++){
                if (ks < kmaxY){
                    bf16x8 wfA = *(const bf16x8*)&Ws[(i0 + l15)*72 + ks*32 + l4*8];
                    #pragma unroll
                    for (int np=0;np<4;np++)
                        yacc[m][np] = __builtin_amdgcn_mfma_f32_16x16x32_bf16(wfA, bfx[np][ks], yacc[m][np], 0, 0, 0);
                }
            }
        }
    }

    float Dh = D_param[h];
    #pragma unroll
    for (int m=0;m<4;m++){
        int i0 = (m*4 + w)*16;
        #pragma unroll
        for (int np=0;np<4;np++){
            int p = np*16 + l15;
            #pragma unroll
            for (int q=0;q<4;q++){
                int i = i0 + l4*4 + q;
                float xv = bfbits2f(xdT[p*264 + i]);
                yh[((size_t)bc*CHUNK + i)*DINNER + h*HEADDIM + p] = f2bf(yacc[m][np][q] + Dh*xv);
            }
        }
    }
}

// ---------------------------------------------------------------------------
// K9: g = RMSNorm(yh * silu(z))*norm_w -> bf16 g
// ---------------------------------------------------------------------------
__global__ __launch_bounds__(256) void gate_norm(
    const ushort_t* __restrict__ yh, const __hip_bfloat16* __restrict__ z,
    const float* __restrict__ norm_w, __hip_bfloat16* __restrict__ g)
{
    int row = blockIdx.x;
    int t = threadIdx.x;
    const ushort_t* yr = yh + (size_t)row*DINNER + t*8;
    const ushort_t* zr = (const ushort_t*)z + (size_t)row*DINNER + t*8;
    bf16x8 yv = *(const bf16x8*)yr;
    bf16x8 zv8 = *(const bf16x8*)zr;
    float v[8];
    float ss = 0.f;
    #pragma unroll
    for (int e=0;e<8;e++){
        float y = bfbits2f(((const ushort_t*)&yv)[e]);
        float zz = bfbits2f(((const ushort_t*)&zv8)[e]);
        float gv = y * (zz / (1.f + __expf(-zz)));
        v[e] = gv; ss += gv*gv;
    }
    #pragma unroll
    for (int off=32; off>=1; off>>=1) ss += __shfl_xor(ss, off);
    __shared__ float red[4];
    if ((t & 63) == 0) red[t >> 6] = ss;
    __syncthreads();
    float tot = red[0]+red[1]+red[2]+red[3];
    float scale = rsqrtf(tot * (1.f/DINNER) + 1e-5f);
    float4 w0 = *(const float4*)&norm_w[t*8];
    float4 w1 = *(const float4*)&norm_w[t*8+4];
    float nw[8] = {w0.x,w0.y,w0.z,w0.w,w1.x,w1.y,w1.z,w1.w};
    ushort_t o[8];
    #pragma unroll
    for (int e=0;e<8;e++) o[e] = f2bf(v[e]*scale*nw[e]);
    *(uint4*)((ushort_t*)g + (size_t)row*DINNER + t*8) = *(const uint4*)o;
}

// ---------------------------------------------------------------------------
extern "C" void kernel_launch(void* const* d_in, const int* in_sizes, int n_in,
                              void* d_out, int out_size, void* d_ws, size_t ws_size,
                              hipStream_t stream)
{
    const float* u       = (const float*)d_in[0];
    const float* W_in    = (const float*)d_in[1];
    const float* conv_w  = (const float*)d_in[2];
    const float* conv_b  = (const float*)d_in[3];
    const float* dt_bias = (const float*)d_in[4];
    const float* A_log   = (const float*)d_in[5];
    const float* D_param = (const float*)d_in[6];
    const float* norm_w  = (const float*)d_in[7];
    const float* W_out   = (const float*)d_in[8];
    float* out = (float*)d_out;

    char* p = (char*)d_ws;
    auto take = [&](size_t n){ char* r = p; p += (n + 255) & ~(size_t)255; return r; };

    __hip_bfloat16* z       = (__hip_bfloat16*)take((size_t)BL*DINNER*2);
    __hip_bfloat16* xbc_raw = (__hip_bfloat16*)take((size_t)BL*CONVDIM*2);
    __hip_bfloat16* xbc     = (__hip_bfloat16*)take((size_t)BL*CONVDIM*2);
    float* dtp     = (float*)take((size_t)BL*NHEADS*4);
    float* dAcs    = (float*)take((size_t)BL*NHEADS*4);
    float* states  = (float*)take((size_t)B_N*NCHUNK*NHEADS*HEADDIM*DSTATE*4);
    ushort_t* yh   = (ushort_t*)take((size_t)BL*DINNER*2);
    ushort_t* S_T  = (ushort_t*)take((size_t)B_N*NCHUNK*CHUNK*264*2);
    ushort_t* u_bf  = (ushort_t*)take((size_t)BL*DMODEL*2);
    ushort_t* Wi_bf = (ushort_t*)take((size_t)DINPROJ*DMODEL*2);
    ushort_t* Wo_bf = (ushort_t*)take((size_t)DMODEL*DINNER*2);
    float* wT       = (float*)take((size_t)DCONV*CONVDIM*4);
    __hip_bfloat16* g = z;   // alias: z dead after gate_norm's elementwise read

    cvt_bf16<<<dim3((BL*DMODEL/8 + 255)/256), 256, 0, stream>>>(u, u_bf, BL*DMODEL/8);
    cvt_bf16<<<dim3((DINPROJ*DMODEL/8 + 255)/256), 256, 0, stream>>>(W_in, Wi_bf, DINPROJ*DMODEL/8);
    cvt_bf16<<<dim3((DMODEL*DINNER/8 + 255)/256), 256, 0, stream>>>(W_out, Wo_bf, DMODEL*DINNER/8);
    cvt_wT<<<dim3((CONVDIM+255)/256), 256, 0, stream>>>(conv_w, wT);

    // in-proj: 256^2 pipelined (M tiles 32 x N tiles 18 = 576 wg, %8==0)
    gemm_inproj_8ph<<<dim3(32*18), 512, 0, stream>>>(
        u_bf, Wi_bf, (ushort_t*)z, (ushort_t*)xbc_raw, dt_bias, dtp);

    conv_silu<<<dim3(BL*(CONVDIM/8)/256), 256, 0, stream>>>(xbc_raw, wT, conv_b, xbc);
    dt_cumsum<<<dim3(B_N*NHEADS*NCHUNK), 256, 0, stream>>>(dtp, A_log, dAcs);
    bc_scores_mfma<<<dim3(B_N*NCHUNK), 256, 0, stream>>>(xbc, S_T);
    ssd_states_mfma<<<dim3(B_N*NCHUNK, NHEADS/4), 256, 0, stream>>>(xbc, dtp, dAcs, states);
    scan_states<<<dim3((B_N*NHEADS*HEADDIM*DSTATE)/256), 256, 0, stream>>>(states, dAcs);
    ssd_mfma<<<dim3(B_N*NCHUNK, NHEADS), 256, 0, stream>>>(xbc, dtp, dAcs, states, S_T, D_param, yh);
    gate_norm<<<dim3(BL), 256, 0, stream>>>(yh, z, norm_w, g);

    // out-proj: proven 2-phase 128^2 (64 x 8 = 512 wg)
    gemm_bt_mfma<DINNER,8><<<dim3(64*8), 256, 0, stream>>>(
        (const ushort_t*)g, Wo_bf, out);
}

// Round 13
// 367.978 us; speedup vs baseline: 1.0951x; 1.0951x over previous
//
#include <hip/hip_runtime.h>
#include <hip/hip_bf16.h>
#include <math.h>

#define B_N     4
#define L_N     2048
#define DMODEL  1024
#define DSTATE  128
#define DCONV   4
#define HEADDIM 64
#define CHUNK   256
#define DINNER  2048
#define NHEADS  32
#define CONVDIM 2304
#define DINPROJ 4384
#define NCHUNK  8
#define BL      (B_N*L_N)

typedef unsigned short ushort_t;
typedef unsigned int   uint_t;

typedef __attribute__((ext_vector_type(8))) short bf16x8;
typedef __attribute__((ext_vector_type(4))) float f32x4;

__device__ __forceinline__ float bfbits2f(ushort_t u){
    union { uint_t i; float f; } v; v.i = ((uint_t)u) << 16; return v.f;
}
__device__ __forceinline__ ushort_t f2bf(float f){
    union { float f; uint_t i; } v; v.f = f;
    uint_t r = v.i + 0x7FFF + ((v.i >> 16) & 1);
    return (ushort_t)(r >> 16);
}
__device__ __forceinline__ void gload_lds16(const void* g, void* l){
    __builtin_amdgcn_global_load_lds(
        (const __attribute__((address_space(1))) unsigned int*)g,
        (__attribute__((address_space(3))) unsigned int*)l, 16, 0, 0);
}

// ---------------------------------------------------------------------------
// K0: fused f32 -> bf16 convert for u / W_in / W_out (8 elems/thread)
// ---------------------------------------------------------------------------
#define N_U8  (BL*DMODEL/8)
#define N_WI8 (DINPROJ*DMODEL/8)
#define N_WO8 (DMODEL*DINNER/8)

__global__ __launch_bounds__(256) void cvt_all(
    const float* __restrict__ u, const float* __restrict__ W_in,
    const float* __restrict__ W_out,
    ushort_t* __restrict__ u_bf, ushort_t* __restrict__ Wi_bf,
    ushort_t* __restrict__ Wo_bf)
{
    int i = blockIdx.x*256 + threadIdx.x;
    const float* src; ushort_t* dst; int off;
    if (i < N_U8)                { src = u;     dst = u_bf;  off = i; }
    else if (i < N_U8+N_WI8)     { src = W_in;  dst = Wi_bf; off = i - N_U8; }
    else if (i < N_U8+N_WI8+N_WO8){ src = W_out; dst = Wo_bf; off = i - N_U8 - N_WI8; }
    else return;
    const float4* p = (const float4*)(src + (size_t)off*8);
    float4 a = p[0], b = p[1];
    ushort_t o[8] = { f2bf(a.x), f2bf(a.y), f2bf(a.z), f2bf(a.w),
                      f2bf(b.x), f2bf(b.y), f2bf(b.z), f2bf(b.w) };
    *(uint4*)(dst + (size_t)off*8) = *(const uint4*)o;
}

// ---------------------------------------------------------------------------
// K0b: transpose conv weights: wT[k][c] = cw[c][k]
// ---------------------------------------------------------------------------
__global__ __launch_bounds__(256) void cvt_wT(
    const float* __restrict__ cw, float* __restrict__ wT)
{
    int c = blockIdx.x*256 + threadIdx.x;
    if (c >= CONVDIM) return;
    float4 v = *(const float4*)&cw[c*DCONV];
    wT[0*CONVDIM + c] = v.x;
    wT[1*CONVDIM + c] = v.y;
    wT[2*CONVDIM + c] = v.z;
    wT[3*CONVDIM + c] = v.w;
}

// ---------------------------------------------------------------------------
// K1: bf16 MFMA GEMM, C = A @ B^T. 128x128 tile, BK=32, 4 waves.
// 2-phase double-buffered LDS + XCD-aware bijective swizzle. (R7/R11 config)
// EPI=0: f32 out. EPI=1: in-proj split epilogue.
// ---------------------------------------------------------------------------
template<int KDIM, int NTILES, int EPI>
__global__ __launch_bounds__(256) void gemm_bt_mfma(
    const ushort_t* __restrict__ A, const ushort_t* __restrict__ B,
    float* __restrict__ outf, ushort_t* __restrict__ z, ushort_t* __restrict__ xbc,
    const float* __restrict__ dt_bias, float* __restrict__ dtp)
{
    __shared__ __align__(16) ushort_t Asl[2][128*32];
    __shared__ __align__(16) ushort_t Bsl[2][128*32];

    int nwg = gridDim.x, cpx = nwg >> 3, lin = blockIdx.x;
    int work = (lin & 7)*cpx + (lin >> 3);
    int mtile = work / NTILES, ntile = work % NTILES;
    int m0 = mtile*128, n0 = ntile*128;

    int t = threadIdx.x;
    int l = t & 63, w = t >> 6;
    int wr = w >> 1, wc = w & 1;
    int lr16 = l & 15, kb = l >> 4;
    int srow = t >> 2, skc = (t & 3)*8;

    f32x4 acc[4][4];
    #pragma unroll
    for (int m=0;m<4;m++){
        #pragma unroll
        for (int n=0;n<4;n++) acc[m][n] = (f32x4){0.f,0.f,0.f,0.f};
    }

    int br0 = n0 + srow, br1 = n0 + 64 + srow;
    if (EPI == 1){
        br0 = (br0 < DINPROJ) ? br0 : (DINPROJ-1);
        br1 = (br1 < DINPROJ) ? br1 : (DINPROJ-1);
    }

    auto stage = [&](int buf, int k0){
        gload_lds16(A + (size_t)(m0+srow)*KDIM + k0 + skc,    &Asl[buf][t*8]);
        gload_lds16(A + (size_t)(m0+64+srow)*KDIM + k0 + skc, &Asl[buf][2048 + t*8]);
        gload_lds16(B + (size_t)br0*KDIM + k0 + skc,          &Bsl[buf][t*8]);
        gload_lds16(B + (size_t)br1*KDIM + k0 + skc,          &Bsl[buf][2048 + t*8]);
    };

    auto compute = [&](int cur){
        bf16x8 af[4], bfr[4];
        #pragma unroll
        for (int m=0;m<4;m++) af[m]  = *(const bf16x8*)&Asl[cur][(wr*64+m*16+lr16)*32 + kb*8];
        #pragma unroll
        for (int n=0;n<4;n++) bfr[n] = *(const bf16x8*)&Bsl[cur][(wc*64+n*16+lr16)*32 + kb*8];
        __builtin_amdgcn_s_setprio(1);
        #pragma unroll
        for (int m=0;m<4;m++){
            #pragma unroll
            for (int n=0;n<4;n++)
                acc[m][n] = __builtin_amdgcn_mfma_f32_16x16x32_bf16(af[m], bfr[n], acc[m][n], 0, 0, 0);
        }
        __builtin_amdgcn_s_setprio(0);
    };

    stage(0, 0);
    __syncthreads();
    int cur = 0;
    for (int k0=32; k0<KDIM; k0+=32){
        stage(cur^1, k0);
        compute(cur);
        __syncthreads();
        cur ^= 1;
    }
    compute(cur);

    #pragma unroll
    for (int m=0;m<4;m++){
        int rbase = m0 + wr*64 + m*16 + (l>>4)*4;
        #pragma unroll
        for (int n=0;n<4;n++){
            int gcol = n0 + wc*64 + n*16 + lr16;
            f32x4 v = acc[m][n];
            #pragma unroll
            for (int q=0;q<4;q++){
                int row = rbase + q;
                if (EPI == 0) {
                    outf[(size_t)row*DMODEL + gcol] = v[q];
                } else {
                    if (gcol < DINNER) {
                        z[(size_t)row*DINNER + gcol] = f2bf(v[q]);
                    } else if (gcol < DINNER + CONVDIM) {
                        xbc[(size_t)row*CONVDIM + (gcol - DINNER)] = f2bf(v[q]);
                    } else if (gcol < DINPROJ) {
                        int hh = gcol - (DINNER + CONVDIM);
                        float x = v[q] + dt_bias[hh];
                        float sp = (x > 15.f) ? x : log1pf(__expf(x));
                        int bb = row >> 11, ll = row & (L_N-1);
                        dtp[((size_t)bb*NHEADS + hh)*L_N + ll] = sp;
                    }
                }
            }
        }
    }
}

// ---------------------------------------------------------------------------
// K2: causal depthwise conv1d (width 4) + bias + SiLU — bf16x8, wT[k][c]
// ---------------------------------------------------------------------------
__global__ __launch_bounds__(256) void conv_silu(
    const __hip_bfloat16* __restrict__ xraw,
    const float* __restrict__ wT, const float* __restrict__ cb,
    __hip_bfloat16* __restrict__ xout)
{
    int idx = blockIdx.x*256 + threadIdx.x;
    int c8 = (idx % (CONVDIM/8))*8;
    int ml = idx / (CONVDIM/8);
    int b  = ml >> 11, l = ml & (L_N-1);
    const ushort_t* xr = (const ushort_t*)xraw;
    float acc[8];
    {
        float4 b0 = *(const float4*)&cb[c8];
        float4 b1 = *(const float4*)&cb[c8+4];
        acc[0]=b0.x; acc[1]=b0.y; acc[2]=b0.z; acc[3]=b0.w;
        acc[4]=b1.x; acc[5]=b1.y; acc[6]=b1.z; acc[7]=b1.w;
    }
    #pragma unroll
    for (int k=0;k<DCONV;k++){
        int li = l - (DCONV-1) + k;
        if (li >= 0){
            bf16x8 v = *(const bf16x8*)&xr[((size_t)b*L_N + li)*CONVDIM + c8];
            float4 w0 = *(const float4*)&wT[k*CONVDIM + c8];
            float4 w1 = *(const float4*)&wT[k*CONVDIM + c8 + 4];
            float wv[8] = {w0.x,w0.y,w0.z,w0.w,w1.x,w1.y,w1.z,w1.w};
            #pragma unroll
            for (int e=0;e<8;e++)
                acc[e] += wv[e] * bfbits2f(((const ushort_t*)&v)[e]);
        }
    }
    ushort_t o[8];
    #pragma unroll
    for (int e=0;e<8;e++){
        float s = acc[e] / (1.f + __expf(-acc[e]));
        o[e] = f2bf(s);
    }
    *(uint4*)((ushort_t*)xout + (size_t)idx*8) = *(const uint4*)o;
}

// ---------------------------------------------------------------------------
// K3: dA = dt*A; inclusive cumsum within each chunk
// ---------------------------------------------------------------------------
__global__ __launch_bounds__(256) void dt_cumsum(
    const float* __restrict__ dtp, const float* __restrict__ A_log,
    float* __restrict__ dAcs)
{
    int blk = blockIdx.x;
    int c  = blk % NCHUNK;
    int bh = blk / NCHUNK;
    int h  = bh & (NHEADS-1);
    int t  = threadIdx.x;
    float A = -__expf(A_log[h]);
    __shared__ float sm[CHUNK];
    float v = dtp[(size_t)bh*L_N + c*CHUNK + t] * A;
    sm[t] = v;
    __syncthreads();
    for (int off=1; off<CHUNK; off<<=1){
        float add = (t >= off) ? sm[t-off] : 0.f;
        __syncthreads();
        sm[t] += add;
        __syncthreads();
    }
    dAcs[(size_t)bh*L_N + c*CHUNK + t] = sm[t];
}

// ---------------------------------------------------------------------------
// K4: S_T[bc][j][i] = sum_n B[j,n]*C[i,n]  (bf16), once per chunk
// ---------------------------------------------------------------------------
__global__ __launch_bounds__(256) void bc_scores_mfma(
    const __hip_bfloat16* __restrict__ xbc, ushort_t* __restrict__ S_T)
{
    __shared__ __align__(16) ushort_t Bs2[256*136];
    __shared__ __align__(16) ushort_t Cs2[256*136];
    int bc = blockIdx.x;
    int t = threadIdx.x;
    int l = t & 63, w = t >> 6;
    int l15 = l & 15, l4 = l >> 4;
    const ushort_t* xb = (const ushort_t*)xbc;
    const size_t rowbase = (size_t)bc*CHUNK*CONVDIM;

    #pragma unroll
    for (int ps=0; ps<16; ps++){
        int idx = ps*256 + t;
        int r = idx >> 4, ck = idx & 15;
        *(uint4*)&Bs2[r*136 + ck*8] =
            *(const uint4*)&xb[rowbase + (size_t)r*CONVDIM + DINNER + ck*8];
        *(uint4*)&Cs2[r*136 + ck*8] =
            *(const uint4*)&xb[rowbase + (size_t)r*CONVDIM + (DINNER+DSTATE) + ck*8];
    }
    __syncthreads();

    ushort_t* Sb = S_T + (size_t)bc*CHUNK*264;
    for (int if4 = w; if4 < 4; if4++){
        f32x4 acc[4][4];
        #pragma unroll
        for (int jf=0;jf<4;jf++){
            #pragma unroll
            for (int ir=0;ir<4;ir++) acc[jf][ir] = (f32x4){0.f,0.f,0.f,0.f};
        }
        #pragma unroll
        for (int k=0;k<4;k++){
            bf16x8 af[4], bfC[4];
            #pragma unroll
            for (int jf=0;jf<4;jf++)
                af[jf] = *(const bf16x8*)&Bs2[(w*64 + jf*16 + l15)*136 + k*32 + l4*8];
            #pragma unroll
            for (int ir=0;ir<4;ir++)
                bfC[ir] = *(const bf16x8*)&Cs2[(if4*64 + ir*16 + l15)*136 + k*32 + l4*8];
            #pragma unroll
            for (int jf=0;jf<4;jf++){
                #pragma unroll
                for (int ir=0;ir<4;ir++)
                    acc[jf][ir] = __builtin_amdgcn_mfma_f32_16x16x32_bf16(af[jf], bfC[ir], acc[jf][ir], 0, 0, 0);
            }
        }
        #pragma unroll
        for (int jf=0;jf<4;jf++){
            #pragma unroll
            for (int ir=0;ir<4;ir++){
                #pragma unroll
                for (int q=0;q<4;q++){
                    int j = w*64 + jf*16 + l4*4 + q;
                    int i = if4*64 + ir*16 + l15;
                    Sb[(size_t)j*264 + i] = f2bf(acc[jf][ir][q]);
                }
            }
        }
    }
}

// ---------------------------------------------------------------------------
// K6: states via MFMA, 4 heads per block
// ---------------------------------------------------------------------------
__device__ __forceinline__ int swz264(int row, int col){
    return row*264 + (col ^ (((row>>3)&7)<<3));
}

__global__ __launch_bounds__(256) void ssd_states_mfma(
    const __hip_bfloat16* __restrict__ xbc,
    const float* __restrict__ dtp, const float* __restrict__ dAcs,
    float* __restrict__ states)
{
    __shared__ __align__(16) ushort_t xdT[64*264];
    __shared__ __align__(16) ushort_t BT[128*264];
    __shared__ float coef_s[CHUNK];
    int bc = blockIdx.x, hg = blockIdx.y;
    int b = bc >> 3, c = bc & 7;
    int t = threadIdx.x;
    int l = t & 63, w = t >> 6;
    int l15 = l & 15, l4 = l >> 4;
    const ushort_t* xb = (const ushort_t*)xbc;
    const size_t rowbase = (size_t)bc*CHUNK*CONVDIM;

    #pragma unroll
    for (int ps=0; ps<16; ps++){
        int idx = ps*256 + t;
        int j = idx >> 4, n0 = (idx & 15)*8;
        bf16x8 v = *(const bf16x8*)&xb[rowbase + (size_t)j*CONVDIM + DINNER + n0];
        #pragma unroll
        for (int e=0;e<8;e++)
            BT[swz264(n0+e, j)] = ((const ushort_t*)&v)[e];
    }

    for (int hh=0; hh<4; hh++){
        int h = hg*4 + hh;
        size_t dbase = ((size_t)b*NHEADS + h)*L_N + c*CHUNK;
        float last = dAcs[dbase + CHUNK-1];
        float cf = __expf(last - dAcs[dbase + t]) * dtp[dbase + t];
        coef_s[t] = cf;
        __syncthreads();

        #pragma unroll
        for (int ps=0; ps<8; ps++){
            int idx = ps*256 + t;
            int j = idx >> 3, p0 = (idx & 7)*8;
            float cj = coef_s[j];
            bf16x8 v = *(const bf16x8*)&xb[rowbase + (size_t)j*CONVDIM + h*HEADDIM + p0];
            #pragma unroll
            for (int e=0;e<8;e++)
                xdT[swz264(p0+e, j)] = f2bf(cj * bfbits2f(((const ushort_t*)&v)[e]));
        }
        __syncthreads();

        f32x4 acc[4][2];
        #pragma unroll
        for (int pf=0;pf<4;pf++){
            #pragma unroll
            for (int nf=0;nf<2;nf++) acc[pf][nf] = (f32x4){0.f,0.f,0.f,0.f};
        }

        #pragma unroll
        for (int k=0;k<8;k++){
            bf16x8 af[4], bv[2];
            #pragma unroll
            for (int pf=0;pf<4;pf++)
                af[pf] = *(const bf16x8*)&xdT[swz264(pf*16 + l15, k*32 + l4*8)];
            #pragma unroll
            for (int nf=0;nf<2;nf++)
                bv[nf] = *(const bf16x8*)&BT[swz264(w*32 + nf*16 + l15, k*32 + l4*8)];
            #pragma unroll
            for (int pf=0;pf<4;pf++){
                #pragma unroll
                for (int nf=0;nf<2;nf++)
                    acc[pf][nf] = __builtin_amdgcn_mfma_f32_16x16x32_bf16(af[pf], bv[nf], acc[pf][nf], 0, 0, 0);
            }
        }

        float* sb = states + (size_t)(bc*NHEADS + h)*HEADDIM*DSTATE;
        #pragma unroll
        for (int pf=0;pf<4;pf++){
            #pragma unroll
            for (int nf=0;nf<2;nf++){
                #pragma unroll
                for (int q=0;q<4;q++){
                    int p = pf*16 + l4*4 + q;
                    int n = w*32 + nf*16 + l15;
                    sb[(size_t)p*DSTATE + n] = acc[pf][nf][q];
                }
            }
        }
    }
}

// ---------------------------------------------------------------------------
// K7: inter-chunk scan
// ---------------------------------------------------------------------------
__global__ __launch_bounds__(256) void scan_states(
    float* __restrict__ states, const float* __restrict__ dAcs)
{
    int idx = blockIdx.x*256 + threadIdx.x;
    int n  = idx & 127;
    int p  = (idx >> 7) & 63;
    int bh = idx >> 13;
    int b  = bh >> 5, h = bh & 31;
    float carry = 0.f;
    for (int c=0;c<NCHUNK;c++){
        size_t off = (((size_t)((b*NCHUNK + c)*NHEADS + h))*HEADDIM + p)*DSTATE + n;
        float s = states[off];
        states[off] = carry;
        float cd = __expf(dAcs[((size_t)b*NHEADS + h)*L_N + c*CHUNK + (CHUNK-1)]);
        carry = carry * cd + s;
    }
}

// ---------------------------------------------------------------------------
// K5: fused MFMA SSD -> bf16 yh
// ---------------------------------------------------------------------------
__global__ __launch_bounds__(256) void ssd_mfma(
    const __hip_bfloat16* __restrict__ xbc,
    const float* __restrict__ dtp, const float* __restrict__ dAcs,
    const float* __restrict__ states, const ushort_t* __restrict__ S_T,
    const float* __restrict__ D_param, ushort_t* __restrict__ yh)
{
    __shared__ __align__(16) ushort_t Ws[256*72];
    __shared__ __align__(16) ushort_t xdT[64*264];
    __shared__ float da_s[CHUNK];
    __shared__ float dt_s[CHUNK];

    int bc = blockIdx.x, h = blockIdx.y;
    int b = bc >> 3, c = bc & 7;
    int t = threadIdx.x;
    int l = t & 63, w = t >> 6;
    int l15 = l & 15, l4 = l >> 4;

    const ushort_t* xb = (const ushort_t*)xbc;
    const size_t rowbase = (size_t)bc*CHUNK*CONVDIM;

    da_s[t] = dAcs[((size_t)b*NHEADS + h)*L_N + c*CHUNK + t];
    dt_s[t] = dtp[((size_t)b*NHEADS + h)*L_N + c*CHUNK + t];

    #pragma unroll
    for (int ps=0; ps<8; ps++){
        int idx = ps*256 + t;
        int j = idx >> 3, p0 = (idx & 7)*8;
        bf16x8 v = *(const bf16x8*)&xb[rowbase + (size_t)j*CONVDIM + h*HEADDIM + p0];
        #pragma unroll
        for (int e=0;e<8;e++) xdT[(p0+e)*264 + j] = ((const ushort_t*)&v)[e];
    }
    __syncthreads();

    f32x4 yacc[4][4];
    #pragma unroll
    for (int m=0;m<4;m++){
        #pragma unroll
        for (int np=0;np<4;np++) yacc[m][np] = (f32x4){0.f,0.f,0.f,0.f};
    }

    const ushort_t* cbase = xb + rowbase + (size_t)l15*CONVDIM + (DINNER+DSTATE) + l4*8;
    const float*    pbase = states + (size_t)(bc*NHEADS + h)*HEADDIM*DSTATE
                                   + (size_t)l15*DSTATE + l4*8;
    #pragma unroll
    for (int k=0;k<4;k++){
        bf16x8 bfk[4];
        #pragma unroll
        for (int np=0;np<4;np++){
            const float* pr = pbase + (size_t)(np*16)*DSTATE + k*32;
            float4 a = *(const float4*)pr;
            float4 bq = *(const float4*)(pr + 4);
            bf16x8 r;
            r[0]=(short)f2bf(a.x);  r[1]=(short)f2bf(a.y);
            r[2]=(short)f2bf(a.z);  r[3]=(short)f2bf(a.w);
            r[4]=(short)f2bf(bq.x); r[5]=(short)f2bf(bq.y);
            r[6]=(short)f2bf(bq.z); r[7]=(short)f2bf(bq.w);
            bfk[np] = r;
        }
        #pragma unroll
        for (int m=0;m<4;m++){
            int i0 = (m*4 + w)*16;
            bf16x8 af = *(const bf16x8*)(cbase + (size_t)i0*CONVDIM + k*32);
            #pragma unroll
            for (int np=0;np<4;np++)
                yacc[m][np] = __builtin_amdgcn_mfma_f32_16x16x32_bf16(af, bfk[np], yacc[m][np], 0, 0, 0);
        }
    }
    #pragma unroll
    for (int m=0;m<4;m++){
        int i0 = (m*4 + w)*16;
        #pragma unroll
        for (int q=0;q<4;q++){
            float e = __expf(da_s[i0 + l4*4 + q]);
            #pragma unroll
            for (int np=0;np<4;np++) yacc[m][np][q] *= e;
        }
    }

    const ushort_t* Sb = S_T + (size_t)bc*CHUNK*264;
    for (int jp=0; jp<4; jp++){
        bf16x8 bfx[4][2];
        #pragma unroll
        for (int np=0;np<4;np++){
            #pragma unroll
            for (int ks=0;ks<2;ks++)
                bfx[np][ks] = *(const bf16x8*)&xdT[(np*16 + l15)*264 + jp*64 + ks*32 + l4*8];
        }

        #pragma unroll
        for (int m=0;m<4;m++){
            int i0 = (m*4 + w)*16;
            int imax = i0 + 15;
            int kmaxY = (jp*64 <= imax ? 1 : 0) + (jp*64+32 <= imax ? 1 : 0);
            if (kmaxY == 0) continue;
            int nmax = 2*kmaxY;

            float dai[4];
            #pragma unroll
            for (int q=0;q<4;q++) dai[q] = da_s[i0 + l4*4 + q];
            #pragma unroll
            for (int n=0;n<4;n++){
                if (n < nmax){
                    int jcol = jp*64 + n*16 + l15;
                    float daj = da_s[jcol], dtj = dt_s[jcol];
                    ushort_t sv[4];
                    *(uint2*)sv = *(const uint2*)&Sb[(size_t)jcol*264 + i0 + l4*4];
                    #pragma unroll
                    for (int q=0;q<4;q++){
                        int i = i0 + l4*4 + q;
                        float wv = 0.f;
                        if (jcol <= i) wv = __expf(dai[q] - daj) * dtj * bfbits2f(sv[q]);
                        Ws[i*72 + n*16 + l15] = f2bf(wv);
                    }
                }
            }
            #pragma unroll
            for (int ks=0;ks<2;ks++){
                if (ks < kmaxY){
                    bf16x8 wfA = *(const bf16x8*)&Ws[(i0 + l15)*72 + ks*32 + l4*8];
                    #pragma unroll
                    for (int np=0;np<4;np++)
                        yacc[m][np] = __builtin_amdgcn_mfma_f32_16x16x32_bf16(wfA, bfx[np][ks], yacc[m][np], 0, 0, 0);
                }
            }
        }
    }

    float Dh = D_param[h];
    #pragma unroll
    for (int m=0;m<4;m++){
        int i0 = (m*4 + w)*16;
        #pragma unroll
        for (int np=0;np<4;np++){
            int p = np*16 + l15;
            #pragma unroll
            for (int q=0;q<4;q++){
                int i = i0 + l4*4 + q;
                float xv = bfbits2f(xdT[p*264 + i]);
                yh[((size_t)bc*CHUNK + i)*DINNER + h*HEADDIM + p] = f2bf(yacc[m][np][q] + Dh*xv);
            }
        }
    }
}

// ---------------------------------------------------------------------------
// K9: g = RMSNorm(yh * silu(z))*norm_w -> bf16 g
// ---------------------------------------------------------------------------
__global__ __launch_bounds__(256) void gate_norm(
    const ushort_t* __restrict__ yh, const __hip_bfloat16* __restrict__ z,
    const float* __restrict__ norm_w, __hip_bfloat16* __restrict__ g)
{
    int row = blockIdx.x;
    int t = threadIdx.x;
    const ushort_t* yr = yh + (size_t)row*DINNER + t*8;
    const ushort_t* zr = (const ushort_t*)z + (size_t)row*DINNER + t*8;
    bf16x8 yv = *(const bf16x8*)yr;
    bf16x8 zv8 = *(const bf16x8*)zr;
    float v[8];
    float ss = 0.f;
    #pragma unroll
    for (int e=0;e<8;e++){
        float y = bfbits2f(((const ushort_t*)&yv)[e]);
        float zz = bfbits2f(((const ushort_t*)&zv8)[e]);
        float gv = y * (zz / (1.f + __expf(-zz)));
        v[e] = gv; ss += gv*gv;
    }
    #pragma unroll
    for (int off=32; off>=1; off>>=1) ss += __shfl_xor(ss, off);
    __shared__ float red[4];
    if ((t & 63) == 0) red[t >> 6] = ss;
    __syncthreads();
    float tot = red[0]+red[1]+red[2]+red[3];
    float scale = rsqrtf(tot * (1.f/DINNER) + 1e-5f);
    float4 w0 = *(const float4*)&norm_w[t*8];
    float4 w1 = *(const float4*)&norm_w[t*8+4];
    float nw[8] = {w0.x,w0.y,w0.z,w0.w,w1.x,w1.y,w1.z,w1.w};
    ushort_t o[8];
    #pragma unroll
    for (int e=0;e<8;e++) o[e] = f2bf(v[e]*scale*nw[e]);
    *(uint4*)((ushort_t*)g + (size_t)row*DINNER + t*8) = *(const uint4*)o;
}

// ---------------------------------------------------------------------------
extern "C" void kernel_launch(void* const* d_in, const int* in_sizes, int n_in,
                              void* d_out, int out_size, void* d_ws, size_t ws_size,
                              hipStream_t stream)
{
    const float* u       = (const float*)d_in[0];
    const float* W_in    = (const float*)d_in[1];
    const float* conv_w  = (const float*)d_in[2];
    const float* conv_b  = (const float*)d_in[3];
    const float* dt_bias = (const float*)d_in[4];
    const float* A_log   = (const float*)d_in[5];
    const float* D_param = (const float*)d_in[6];
    const float* norm_w  = (const float*)d_in[7];
    const float* W_out   = (const float*)d_in[8];
    float* out = (float*)d_out;

    char* p = (char*)d_ws;
    auto take = [&](size_t n){ char* r = p; p += (n + 255) & ~(size_t)255; return r; };

    __hip_bfloat16* z       = (__hip_bfloat16*)take((size_t)BL*DINNER*2);
    __hip_bfloat16* xbc_raw = (__hip_bfloat16*)take((size_t)BL*CONVDIM*2);
    __hip_bfloat16* xbc     = (__hip_bfloat16*)take((size_t)BL*CONVDIM*2);
    float* dtp     = (float*)take((size_t)BL*NHEADS*4);
    float* dAcs    = (float*)take((size_t)BL*NHEADS*4);
    float* states  = (float*)take((size_t)B_N*NCHUNK*NHEADS*HEADDIM*DSTATE*4);
    ushort_t* yh   = (ushort_t*)take((size_t)BL*DINNER*2);
    ushort_t* S_T  = (ushort_t*)take((size_t)B_N*NCHUNK*CHUNK*264*2);
    ushort_t* u_bf  = (ushort_t*)take((size_t)BL*DMODEL*2);
    ushort_t* Wi_bf = (ushort_t*)take((size_t)DINPROJ*DMODEL*2);
    ushort_t* Wo_bf = (ushort_t*)take((size_t)DMODEL*DINNER*2);
    float* wT       = (float*)take((size_t)DCONV*CONVDIM*4);
    __hip_bfloat16* g = z;   // alias: z dead after gate_norm's elementwise read

    cvt_all<<<dim3((N_U8+N_WI8+N_WO8 + 255)/256), 256, 0, stream>>>(
        u, W_in, W_out, u_bf, Wi_bf, Wo_bf);
    cvt_wT<<<dim3((CONVDIM+255)/256), 256, 0, stream>>>(conv_w, wT);

    // in-proj: proven 2-phase 128^2 (64 x 35 = 2240 wg)
    gemm_bt_mfma<DMODEL,35,1><<<dim3(64*35), 256, 0, stream>>>(
        u_bf, Wi_bf, nullptr, (ushort_t*)z, (ushort_t*)xbc_raw, dt_bias, dtp);

    conv_silu<<<dim3(BL*(CONVDIM/8)/256), 256, 0, stream>>>(xbc_raw, wT, conv_b, xbc);
    dt_cumsum<<<dim3(B_N*NHEADS*NCHUNK), 256, 0, stream>>>(dtp, A_log, dAcs);
    bc_scores_mfma<<<dim3(B_N*NCHUNK), 256, 0, stream>>>(xbc, S_T);
    ssd_states_mfma<<<dim3(B_N*NCHUNK, NHEADS/4), 256, 0, stream>>>(xbc, dtp, dAcs, states);
    scan_states<<<dim3((B_N*NHEADS*HEADDIM*DSTATE)/256), 256, 0, stream>>>(states, dAcs);
    ssd_mfma<<<dim3(B_N*NCHUNK, NHEADS), 256, 0, stream>>>(xbc, dtp, dAcs, states, S_T, D_param, yh);
    gate_norm<<<dim3(BL), 256, 0, stream>>>(yh, z, norm_w, g);

    // out-proj: proven 2-phase 128^2 (64 x 8 = 512 wg)
    gemm_bt_mfma<DINNER,8,0><<<dim3(64*8), 256, 0, stream>>>(
        (const ushort_t*)g, Wo_bf, out, nullptr, nullptr, nullptr, nullptr);
}

// Round 14
// 352.515 us; speedup vs baseline: 1.1431x; 1.0439x over previous
//
#include <hip/hip_runtime.h>
#include <hip/hip_bf16.h>
#include <math.h>

#define B_N     4
#define L_N     2048
#define DMODEL  1024
#define DSTATE  128
#define DCONV   4
#define HEADDIM 64
#define CHUNK   256
#define DINNER  2048
#define NHEADS  32
#define CONVDIM 2304
#define DINPROJ 4384
#define NCHUNK  8
#define BL      (B_N*L_N)

typedef unsigned short ushort_t;
typedef unsigned int   uint_t;

typedef __attribute__((ext_vector_type(8))) short bf16x8;
typedef __attribute__((ext_vector_type(4))) float f32x4;

__device__ __forceinline__ float bfbits2f(ushort_t u){
    union { uint_t i; float f; } v; v.i = ((uint_t)u) << 16; return v.f;
}
__device__ __forceinline__ ushort_t f2bf(float f){
    union { float f; uint_t i; } v; v.f = f;
    uint_t r = v.i + 0x7FFF + ((v.i >> 16) & 1);
    return (ushort_t)(r >> 16);
}
__device__ __forceinline__ void gload_lds16(const void* g, void* l){
    __builtin_amdgcn_global_load_lds(
        (const __attribute__((address_space(1))) unsigned int*)g,
        (__attribute__((address_space(3))) unsigned int*)l, 16, 0, 0);
}

// ---------------------------------------------------------------------------
// K0: fused f32 -> bf16 convert for u / W_in / W_out (8 elems/thread)
// ---------------------------------------------------------------------------
#define N_U8  (BL*DMODEL/8)
#define N_WI8 (DINPROJ*DMODEL/8)
#define N_WO8 (DMODEL*DINNER/8)

__global__ __launch_bounds__(256) void cvt_all(
    const float* __restrict__ u, const float* __restrict__ W_in,
    const float* __restrict__ W_out,
    ushort_t* __restrict__ u_bf, ushort_t* __restrict__ Wi_bf,
    ushort_t* __restrict__ Wo_bf)
{
    int i = blockIdx.x*256 + threadIdx.x;
    const float* src; ushort_t* dst; int off;
    if (i < N_U8)                { src = u;     dst = u_bf;  off = i; }
    else if (i < N_U8+N_WI8)     { src = W_in;  dst = Wi_bf; off = i - N_U8; }
    else if (i < N_U8+N_WI8+N_WO8){ src = W_out; dst = Wo_bf; off = i - N_U8 - N_WI8; }
    else return;
    const float4* p = (const float4*)(src + (size_t)off*8);
    float4 a = p[0], b = p[1];
    ushort_t o[8] = { f2bf(a.x), f2bf(a.y), f2bf(a.z), f2bf(a.w),
                      f2bf(b.x), f2bf(b.y), f2bf(b.z), f2bf(b.w) };
    *(uint4*)(dst + (size_t)off*8) = *(const uint4*)o;
}

// ---------------------------------------------------------------------------
// K0b: transpose conv weights: wT[k][c] = cw[c][k]
// ---------------------------------------------------------------------------
__global__ __launch_bounds__(256) void cvt_wT(
    const float* __restrict__ cw, float* __restrict__ wT)
{
    int c = blockIdx.x*256 + threadIdx.x;
    if (c >= CONVDIM) return;
    float4 v = *(const float4*)&cw[c*DCONV];
    wT[0*CONVDIM + c] = v.x;
    wT[1*CONVDIM + c] = v.y;
    wT[2*CONVDIM + c] = v.z;
    wT[3*CONVDIM + c] = v.w;
}

// ---------------------------------------------------------------------------
// K1: bf16 MFMA GEMM, C = A @ B^T. 128x128 tile, BK=32, 4 waves.
// 2-phase double-buffered LDS + XCD-aware bijective swizzle. (frozen config)
// ---------------------------------------------------------------------------
template<int KDIM, int NTILES, int EPI>
__global__ __launch_bounds__(256) void gemm_bt_mfma(
    const ushort_t* __restrict__ A, const ushort_t* __restrict__ B,
    float* __restrict__ outf, ushort_t* __restrict__ z, ushort_t* __restrict__ xbc,
    const float* __restrict__ dt_bias, float* __restrict__ dtp)
{
    __shared__ __align__(16) ushort_t Asl[2][128*32];
    __shared__ __align__(16) ushort_t Bsl[2][128*32];

    int nwg = gridDim.x, cpx = nwg >> 3, lin = blockIdx.x;
    int work = (lin & 7)*cpx + (lin >> 3);
    int mtile = work / NTILES, ntile = work % NTILES;
    int m0 = mtile*128, n0 = ntile*128;

    int t = threadIdx.x;
    int l = t & 63, w = t >> 6;
    int wr = w >> 1, wc = w & 1;
    int lr16 = l & 15, kb = l >> 4;
    int srow = t >> 2, skc = (t & 3)*8;

    f32x4 acc[4][4];
    #pragma unroll
    for (int m=0;m<4;m++){
        #pragma unroll
        for (int n=0;n<4;n++) acc[m][n] = (f32x4){0.f,0.f,0.f,0.f};
    }

    int br0 = n0 + srow, br1 = n0 + 64 + srow;
    if (EPI == 1){
        br0 = (br0 < DINPROJ) ? br0 : (DINPROJ-1);
        br1 = (br1 < DINPROJ) ? br1 : (DINPROJ-1);
    }

    auto stage = [&](int buf, int k0){
        gload_lds16(A + (size_t)(m0+srow)*KDIM + k0 + skc,    &Asl[buf][t*8]);
        gload_lds16(A + (size_t)(m0+64+srow)*KDIM + k0 + skc, &Asl[buf][2048 + t*8]);
        gload_lds16(B + (size_t)br0*KDIM + k0 + skc,          &Bsl[buf][t*8]);
        gload_lds16(B + (size_t)br1*KDIM + k0 + skc,          &Bsl[buf][2048 + t*8]);
    };

    auto compute = [&](int cur){
        bf16x8 af[4], bfr[4];
        #pragma unroll
        for (int m=0;m<4;m++) af[m]  = *(const bf16x8*)&Asl[cur][(wr*64+m*16+lr16)*32 + kb*8];
        #pragma unroll
        for (int n=0;n<4;n++) bfr[n] = *(const bf16x8*)&Bsl[cur][(wc*64+n*16+lr16)*32 + kb*8];
        __builtin_amdgcn_s_setprio(1);
        #pragma unroll
        for (int m=0;m<4;m++){
            #pragma unroll
            for (int n=0;n<4;n++)
                acc[m][n] = __builtin_amdgcn_mfma_f32_16x16x32_bf16(af[m], bfr[n], acc[m][n], 0, 0, 0);
        }
        __builtin_amdgcn_s_setprio(0);
    };

    stage(0, 0);
    __syncthreads();
    int cur = 0;
    for (int k0=32; k0<KDIM; k0+=32){
        stage(cur^1, k0);
        compute(cur);
        __syncthreads();
        cur ^= 1;
    }
    compute(cur);

    #pragma unroll
    for (int m=0;m<4;m++){
        int rbase = m0 + wr*64 + m*16 + (l>>4)*4;
        #pragma unroll
        for (int n=0;n<4;n++){
            int gcol = n0 + wc*64 + n*16 + lr16;
            f32x4 v = acc[m][n];
            #pragma unroll
            for (int q=0;q<4;q++){
                int row = rbase + q;
                if (EPI == 0) {
                    outf[(size_t)row*DMODEL + gcol] = v[q];
                } else {
                    if (gcol < DINNER) {
                        z[(size_t)row*DINNER + gcol] = f2bf(v[q]);
                    } else if (gcol < DINNER + CONVDIM) {
                        xbc[(size_t)row*CONVDIM + (gcol - DINNER)] = f2bf(v[q]);
                    } else if (gcol < DINPROJ) {
                        int hh = gcol - (DINNER + CONVDIM);
                        float x = v[q] + dt_bias[hh];
                        float sp = (x > 15.f) ? x : log1pf(__expf(x));
                        int bb = row >> 11, ll = row & (L_N-1);
                        dtp[((size_t)bb*NHEADS + hh)*L_N + ll] = sp;
                    }
                }
            }
        }
    }
}

// ---------------------------------------------------------------------------
// K2: causal depthwise conv1d + bias + SiLU — 2 tokens x 8 channels / thread
// ---------------------------------------------------------------------------
__global__ __launch_bounds__(256) void conv_silu(
    const __hip_bfloat16* __restrict__ xraw,
    const float* __restrict__ wT, const float* __restrict__ cb,
    __hip_bfloat16* __restrict__ xout)
{
    int idx = blockIdx.x*256 + threadIdx.x;       // (BL/2) * (CONVDIM/8)
    int c8 = (idx % (CONVDIM/8))*8;
    int ml = idx / (CONVDIM/8);
    int b  = ml / (L_N/2);
    int l  = (ml % (L_N/2))*2;
    const ushort_t* xr = (const ushort_t*)xraw;

    float wv[4][8];
    #pragma unroll
    for (int k=0;k<DCONV;k++){
        float4 w0 = *(const float4*)&wT[k*CONVDIM + c8];
        float4 w1 = *(const float4*)&wT[k*CONVDIM + c8 + 4];
        wv[k][0]=w0.x; wv[k][1]=w0.y; wv[k][2]=w0.z; wv[k][3]=w0.w;
        wv[k][4]=w1.x; wv[k][5]=w1.y; wv[k][6]=w1.z; wv[k][7]=w1.w;
    }
    float bias[8];
    {
        float4 b0 = *(const float4*)&cb[c8];
        float4 b1 = *(const float4*)&cb[c8+4];
        bias[0]=b0.x; bias[1]=b0.y; bias[2]=b0.z; bias[3]=b0.w;
        bias[4]=b1.x; bias[5]=b1.y; bias[6]=b1.z; bias[7]=b1.w;
    }

    // rows l-3 .. l+1 (5 rows feed 2 outputs)
    float xv[5][8];
    #pragma unroll
    for (int r=0;r<5;r++){
        int li = l - 3 + r;
        if (li >= 0){
            bf16x8 v = *(const bf16x8*)&xr[((size_t)b*L_N + li)*CONVDIM + c8];
            #pragma unroll
            for (int e=0;e<8;e++) xv[r][e] = bfbits2f(((const ushort_t*)&v)[e]);
        } else {
            #pragma unroll
            for (int e=0;e<8;e++) xv[r][e] = 0.f;
        }
    }

    ushort_t o0[8], o1[8];
    #pragma unroll
    for (int e=0;e<8;e++){
        float a0 = bias[e], a1 = bias[e];
        #pragma unroll
        for (int k=0;k<DCONV;k++){
            a0 += wv[k][e]*xv[k][e];      // token l:   rows l-3..l
            a1 += wv[k][e]*xv[k+1][e];    // token l+1: rows l-2..l+1
        }
        o0[e] = f2bf(a0 / (1.f + __expf(-a0)));
        o1[e] = f2bf(a1 / (1.f + __expf(-a1)));
    }
    ushort_t* ob = (ushort_t*)xout + ((size_t)b*L_N + l)*CONVDIM + c8;
    *(uint4*)ob = *(const uint4*)o0;
    *(uint4*)(ob + CONVDIM) = *(const uint4*)o1;
}

// ---------------------------------------------------------------------------
// K3: dA = dt*A; inclusive cumsum within each chunk
// ---------------------------------------------------------------------------
__global__ __launch_bounds__(256) void dt_cumsum(
    const float* __restrict__ dtp, const float* __restrict__ A_log,
    float* __restrict__ dAcs)
{
    int blk = blockIdx.x;
    int c  = blk % NCHUNK;
    int bh = blk / NCHUNK;
    int h  = bh & (NHEADS-1);
    int t  = threadIdx.x;
    float A = -__expf(A_log[h]);
    __shared__ float sm[CHUNK];
    float v = dtp[(size_t)bh*L_N + c*CHUNK + t] * A;
    sm[t] = v;
    __syncthreads();
    for (int off=1; off<CHUNK; off<<=1){
        float add = (t >= off) ? sm[t-off] : 0.f;
        __syncthreads();
        sm[t] += add;
        __syncthreads();
    }
    dAcs[(size_t)bh*L_N + c*CHUNK + t] = sm[t];
}

// ---------------------------------------------------------------------------
// K4: S_T[bc][j][i] = sum_n B[j,n]*C[i,n]  (bf16), once per chunk
// ---------------------------------------------------------------------------
__global__ __launch_bounds__(256) void bc_scores_mfma(
    const __hip_bfloat16* __restrict__ xbc, ushort_t* __restrict__ S_T)
{
    __shared__ __align__(16) ushort_t Bs2[256*136];
    __shared__ __align__(16) ushort_t Cs2[256*136];
    int bc = blockIdx.x;
    int t = threadIdx.x;
    int l = t & 63, w = t >> 6;
    int l15 = l & 15, l4 = l >> 4;
    const ushort_t* xb = (const ushort_t*)xbc;
    const size_t rowbase = (size_t)bc*CHUNK*CONVDIM;

    #pragma unroll
    for (int ps=0; ps<16; ps++){
        int idx = ps*256 + t;
        int r = idx >> 4, ck = idx & 15;
        *(uint4*)&Bs2[r*136 + ck*8] =
            *(const uint4*)&xb[rowbase + (size_t)r*CONVDIM + DINNER + ck*8];
        *(uint4*)&Cs2[r*136 + ck*8] =
            *(const uint4*)&xb[rowbase + (size_t)r*CONVDIM + (DINNER+DSTATE) + ck*8];
    }
    __syncthreads();

    ushort_t* Sb = S_T + (size_t)bc*CHUNK*264;
    for (int if4 = w; if4 < 4; if4++){
        f32x4 acc[4][4];
        #pragma unroll
        for (int jf=0;jf<4;jf++){
            #pragma unroll
            for (int ir=0;ir<4;ir++) acc[jf][ir] = (f32x4){0.f,0.f,0.f,0.f};
        }
        #pragma unroll
        for (int k=0;k<4;k++){
            bf16x8 af[4], bfC[4];
            #pragma unroll
            for (int jf=0;jf<4;jf++)
                af[jf] = *(const bf16x8*)&Bs2[(w*64 + jf*16 + l15)*136 + k*32 + l4*8];
            #pragma unroll
            for (int ir=0;ir<4;ir++)
                bfC[ir] = *(const bf16x8*)&Cs2[(if4*64 + ir*16 + l15)*136 + k*32 + l4*8];
            #pragma unroll
            for (int jf=0;jf<4;jf++){
                #pragma unroll
                for (int ir=0;ir<4;ir++)
                    acc[jf][ir] = __builtin_amdgcn_mfma_f32_16x16x32_bf16(af[jf], bfC[ir], acc[jf][ir], 0, 0, 0);
            }
        }
        #pragma unroll
        for (int jf=0;jf<4;jf++){
            #pragma unroll
            for (int ir=0;ir<4;ir++){
                #pragma unroll
                for (int q=0;q<4;q++){
                    int j = w*64 + jf*16 + l4*4 + q;
                    int i = if4*64 + ir*16 + l15;
                    Sb[(size_t)j*264 + i] = f2bf(acc[jf][ir][q]);
                }
            }
        }
    }
}

// ---------------------------------------------------------------------------
// K6: states via MFMA, 4 heads per block
// ---------------------------------------------------------------------------
__device__ __forceinline__ int swz264(int row, int col){
    return row*264 + (col ^ (((row>>3)&7)<<3));
}

__global__ __launch_bounds__(256) void ssd_states_mfma(
    const __hip_bfloat16* __restrict__ xbc,
    const float* __restrict__ dtp, const float* __restrict__ dAcs,
    float* __restrict__ states)
{
    __shared__ __align__(16) ushort_t xdT[64*264];
    __shared__ __align__(16) ushort_t BT[128*264];
    __shared__ float coef_s[CHUNK];
    int bc = blockIdx.x, hg = blockIdx.y;
    int b = bc >> 3, c = bc & 7;
    int t = threadIdx.x;
    int l = t & 63, w = t >> 6;
    int l15 = l & 15, l4 = l >> 4;
    const ushort_t* xb = (const ushort_t*)xbc;
    const size_t rowbase = (size_t)bc*CHUNK*CONVDIM;

    #pragma unroll
    for (int ps=0; ps<16; ps++){
        int idx = ps*256 + t;
        int j = idx >> 4, n0 = (idx & 15)*8;
        bf16x8 v = *(const bf16x8*)&xb[rowbase + (size_t)j*CONVDIM + DINNER + n0];
        #pragma unroll
        for (int e=0;e<8;e++)
            BT[swz264(n0+e, j)] = ((const ushort_t*)&v)[e];
    }

    for (int hh=0; hh<4; hh++){
        int h = hg*4 + hh;
        size_t dbase = ((size_t)b*NHEADS + h)*L_N + c*CHUNK;
        float last = dAcs[dbase + CHUNK-1];
        float cf = __expf(last - dAcs[dbase + t]) * dtp[dbase + t];
        coef_s[t] = cf;
        __syncthreads();

        #pragma unroll
        for (int ps=0; ps<8; ps++){
            int idx = ps*256 + t;
            int j = idx >> 3, p0 = (idx & 7)*8;
            float cj = coef_s[j];
            bf16x8 v = *(const bf16x8*)&xb[rowbase + (size_t)j*CONVDIM + h*HEADDIM + p0];
            #pragma unroll
            for (int e=0;e<8;e++)
                xdT[swz264(p0+e, j)] = f2bf(cj * bfbits2f(((const ushort_t*)&v)[e]));
        }
        __syncthreads();

        f32x4 acc[4][2];
        #pragma unroll
        for (int pf=0;pf<4;pf++){
            #pragma unroll
            for (int nf=0;nf<2;nf++) acc[pf][nf] = (f32x4){0.f,0.f,0.f,0.f};
        }

        #pragma unroll
        for (int k=0;k<8;k++){
            bf16x8 af[4], bv[2];
            #pragma unroll
            for (int pf=0;pf<4;pf++)
                af[pf] = *(const bf16x8*)&xdT[swz264(pf*16 + l15, k*32 + l4*8)];
            #pragma unroll
            for (int nf=0;nf<2;nf++)
                bv[nf] = *(const bf16x8*)&BT[swz264(w*32 + nf*16 + l15, k*32 + l4*8)];
            __builtin_amdgcn_s_setprio(1);
            #pragma unroll
            for (int pf=0;pf<4;pf++){
                #pragma unroll
                for (int nf=0;nf<2;nf++)
                    acc[pf][nf] = __builtin_amdgcn_mfma_f32_16x16x32_bf16(af[pf], bv[nf], acc[pf][nf], 0, 0, 0);
            }
            __builtin_amdgcn_s_setprio(0);
        }

        float* sb = states + (size_t)(bc*NHEADS + h)*HEADDIM*DSTATE;
        #pragma unroll
        for (int pf=0;pf<4;pf++){
            #pragma unroll
            for (int nf=0;nf<2;nf++){
                #pragma unroll
                for (int q=0;q<4;q++){
                    int p = pf*16 + l4*4 + q;
                    int n = w*32 + nf*16 + l15;
                    sb[(size_t)p*DSTATE + n] = acc[pf][nf][q];
                }
            }
        }
    }
}

// ---------------------------------------------------------------------------
// K7: inter-chunk scan -> prev_bf (bf16)
// ---------------------------------------------------------------------------
__global__ __launch_bounds__(256) void scan_states(
    const float* __restrict__ states, const float* __restrict__ dAcs,
    ushort_t* __restrict__ prev_bf)
{
    int idx = blockIdx.x*256 + threadIdx.x;
    int n  = idx & 127;
    int p  = (idx >> 7) & 63;
    int bh = idx >> 13;
    int b  = bh >> 5, h = bh & 31;
    float carry = 0.f;
    for (int c=0;c<NCHUNK;c++){
        size_t off = (((size_t)((b*NCHUNK + c)*NHEADS + h))*HEADDIM + p)*DSTATE + n;
        prev_bf[off] = f2bf(carry);
        float s = states[off];
        float cd = __expf(dAcs[((size_t)b*NHEADS + h)*L_N + c*CHUNK + (CHUNK-1)]);
        carry = carry * cd + s;
    }
}

// ---------------------------------------------------------------------------
// K5: fused MFMA SSD -> bf16 yh (prev as bf16, setprio on MFMA clusters)
// ---------------------------------------------------------------------------
__global__ __launch_bounds__(256) void ssd_mfma(
    const __hip_bfloat16* __restrict__ xbc,
    const float* __restrict__ dtp, const float* __restrict__ dAcs,
    const ushort_t* __restrict__ prev_bf, const ushort_t* __restrict__ S_T,
    const float* __restrict__ D_param, ushort_t* __restrict__ yh)
{
    __shared__ __align__(16) ushort_t Ws[256*72];
    __shared__ __align__(16) ushort_t xdT[64*264];
    __shared__ float da_s[CHUNK];
    __shared__ float dt_s[CHUNK];

    int bc = blockIdx.x, h = blockIdx.y;
    int b = bc >> 3, c = bc & 7;
    int t = threadIdx.x;
    int l = t & 63, w = t >> 6;
    int l15 = l & 15, l4 = l >> 4;

    const ushort_t* xb = (const ushort_t*)xbc;
    const size_t rowbase = (size_t)bc*CHUNK*CONVDIM;

    da_s[t] = dAcs[((size_t)b*NHEADS + h)*L_N + c*CHUNK + t];
    dt_s[t] = dtp[((size_t)b*NHEADS + h)*L_N + c*CHUNK + t];

    #pragma unroll
    for (int ps=0; ps<8; ps++){
        int idx = ps*256 + t;
        int j = idx >> 3, p0 = (idx & 7)*8;
        bf16x8 v = *(const bf16x8*)&xb[rowbase + (size_t)j*CONVDIM + h*HEADDIM + p0];
        #pragma unroll
        for (int e=0;e<8;e++) xdT[(p0+e)*264 + j] = ((const ushort_t*)&v)[e];
    }
    __syncthreads();

    f32x4 yacc[4][4];
    #pragma unroll
    for (int m=0;m<4;m++){
        #pragma unroll
        for (int np=0;np<4;np++) yacc[m][np] = (f32x4){0.f,0.f,0.f,0.f};
    }

    // ---- Y_off = C @ prev^T (both operands direct from global, L2-hot)
    const ushort_t* cbase = xb + rowbase + (size_t)l15*CONVDIM + (DINNER+DSTATE) + l4*8;
    const ushort_t* pbase = prev_bf + (size_t)(bc*NHEADS + h)*HEADDIM*DSTATE
                                    + (size_t)l15*DSTATE + l4*8;
    #pragma unroll
    for (int k=0;k<4;k++){
        bf16x8 bfk[4];
        #pragma unroll
        for (int np=0;np<4;np++)
            bfk[np] = *(const bf16x8*)(pbase + (size_t)(np*16)*DSTATE + k*32);
        bf16x8 af0 = *(const bf16x8*)(cbase + (size_t)((0*4+w)*16)*CONVDIM + k*32);
        bf16x8 af1 = *(const bf16x8*)(cbase + (size_t)((1*4+w)*16)*CONVDIM + k*32);
        bf16x8 af2 = *(const bf16x8*)(cbase + (size_t)((2*4+w)*16)*CONVDIM + k*32);
        bf16x8 af3 = *(const bf16x8*)(cbase + (size_t)((3*4+w)*16)*CONVDIM + k*32);
        __builtin_amdgcn_s_setprio(1);
        #pragma unroll
        for (int np=0;np<4;np++){
            yacc[0][np] = __builtin_amdgcn_mfma_f32_16x16x32_bf16(af0, bfk[np], yacc[0][np], 0, 0, 0);
            yacc[1][np] = __builtin_amdgcn_mfma_f32_16x16x32_bf16(af1, bfk[np], yacc[1][np], 0, 0, 0);
            yacc[2][np] = __builtin_amdgcn_mfma_f32_16x16x32_bf16(af2, bfk[np], yacc[2][np], 0, 0, 0);
            yacc[3][np] = __builtin_amdgcn_mfma_f32_16x16x32_bf16(af3, bfk[np], yacc[3][np], 0, 0, 0);
        }
        __builtin_amdgcn_s_setprio(0);
    }
    #pragma unroll
    for (int m=0;m<4;m++){
        int i0 = (m*4 + w)*16;
        #pragma unroll
        for (int q=0;q<4;q++){
            float e = __expf(da_s[i0 + l4*4 + q]);
            #pragma unroll
            for (int np=0;np<4;np++) yacc[m][np][q] *= e;
        }
    }

    // ---- Y_diag panels (no barriers: Ws rows wave-private, xdT read-only)
    const ushort_t* Sb = S_T + (size_t)bc*CHUNK*264;
    for (int jp=0; jp<4; jp++){
        bf16x8 bfx[4][2];
        #pragma unroll
        for (int np=0;np<4;np++){
            #pragma unroll
            for (int ks=0;ks<2;ks++)
                bfx[np][ks] = *(const bf16x8*)&xdT[(np*16 + l15)*264 + jp*64 + ks*32 + l4*8];
        }

        #pragma unroll
        for (int m=0;m<4;m++){
            int i0 = (m*4 + w)*16;
            int imax = i0 + 15;
            int kmaxY = (jp*64 <= imax ? 1 : 0) + (jp*64+32 <= imax ? 1 : 0);
            if (kmaxY == 0) continue;
            int nmax = 2*kmaxY;

            float dai[4];
            #pragma unroll
            for (int q=0;q<4;q++) dai[q] = da_s[i0 + l4*4 + q];
            #pragma unroll
            for (int n=0;n<4;n++){
                if (n < nmax){
                    int jcol = jp*64 + n*16 + l15;
                    float daj = da_s[jcol], dtj = dt_s[jcol];
                    ushort_t sv[4];
                    *(uint2*)sv = *(const uint2*)&Sb[(size_t)jcol*264 + i0 + l4*4];
                    #pragma unroll
                    for (int q=0;q<4;q++){
                        int i = i0 + l4*4 + q;
                        float wv = 0.f;
                        if (jcol <= i) wv = __expf(dai[q] - daj) * dtj * bfbits2f(sv[q]);
                        Ws[i*72 + n*16 + l15] = f2bf(wv);
                    }
                }
            }
            __builtin_amdgcn_s_setprio(1);
            #pragma unroll
            for (int ks=0;ks<2;ks++){
                if (ks < kmaxY){
                    bf16x8 wfA = *(const bf16x8*)&Ws[(i0 + l15)*72 + ks*32 + l4*8];
                    #pragma unroll
                    for (int np=0;np<4;np++)
                        yacc[m][np] = __builtin_amdgcn_mfma_f32_16x16x32_bf16(wfA, bfx[np][ks], yacc[m][np], 0, 0, 0);
                }
            }
            __builtin_amdgcn_s_setprio(0);
        }
    }

    float Dh = D_param[h];
    #pragma unroll
    for (int m=0;m<4;m++){
        int i0 = (m*4 + w)*16;
        #pragma unroll
        for (int np=0;np<4;np++){
            int p = np*16 + l15;
            #pragma unroll
            for (int q=0;q<4;q++){
                int i = i0 + l4*4 + q;
                float xv = bfbits2f(xdT[p*264 + i]);
                yh[((size_t)bc*CHUNK + i)*DINNER + h*HEADDIM + p] = f2bf(yacc[m][np][q] + Dh*xv);
            }
        }
    }
}

// ---------------------------------------------------------------------------
// K9: g = RMSNorm(yh * silu(z))*norm_w -> bf16 g
// ---------------------------------------------------------------------------
__global__ __launch_bounds__(256) void gate_norm(
    const ushort_t* __restrict__ yh, const __hip_bfloat16* __restrict__ z,
    const float* __restrict__ norm_w, __hip_bfloat16* __restrict__ g)
{
    int row = blockIdx.x;
    int t = threadIdx.x;
    const ushort_t* yr = yh + (size_t)row*DINNER + t*8;
    const ushort_t* zr = (const ushort_t*)z + (size_t)row*DINNER + t*8;
    bf16x8 yv = *(const bf16x8*)yr;
    bf16x8 zv8 = *(const bf16x8*)zr;
    float v[8];
    float ss = 0.f;
    #pragma unroll
    for (int e=0;e<8;e++){
        float y = bfbits2f(((const ushort_t*)&yv)[e]);
        float zz = bfbits2f(((const ushort_t*)&zv8)[e]);
        float gv = y * (zz / (1.f + __expf(-zz)));
        v[e] = gv; ss += gv*gv;
    }
    #pragma unroll
    for (int off=32; off>=1; off>>=1) ss += __shfl_xor(ss, off);
    __shared__ float red[4];
    if ((t & 63) == 0) red[t >> 6] = ss;
    __syncthreads();
    float tot = red[0]+red[1]+red[2]+red[3];
    float scale = rsqrtf(tot * (1.f/DINNER) + 1e-5f);
    float4 w0 = *(const float4*)&norm_w[t*8];
    float4 w1 = *(const float4*)&norm_w[t*8+4];
    float nw[8] = {w0.x,w0.y,w0.z,w0.w,w1.x,w1.y,w1.z,w1.w};
    ushort_t o[8];
    #pragma unroll
    for (int e=0;e<8;e++) o[e] = f2bf(v[e]*scale*nw[e]);
    *(uint4*)((ushort_t*)g + (size_t)row*DINNER + t*8) = *(const uint4*)o;
}

// ---------------------------------------------------------------------------
extern "C" void kernel_launch(void* const* d_in, const int* in_sizes, int n_in,
                              void* d_out, int out_size, void* d_ws, size_t ws_size,
                              hipStream_t stream)
{
    const float* u       = (const float*)d_in[0];
    const float* W_in    = (const float*)d_in[1];
    const float* conv_w  = (const float*)d_in[2];
    const float* conv_b  = (const float*)d_in[3];
    const float* dt_bias = (const float*)d_in[4];
    const float* A_log   = (const float*)d_in[5];
    const float* D_param = (const float*)d_in[6];
    const float* norm_w  = (const float*)d_in[7];
    const float* W_out   = (const float*)d_in[8];
    float* out = (float*)d_out;

    char* p = (char*)d_ws;
    auto take = [&](size_t n){ char* r = p; p += (n + 255) & ~(size_t)255; return r; };

    __hip_bfloat16* z       = (__hip_bfloat16*)take((size_t)BL*DINNER*2);
    __hip_bfloat16* xbc_raw = (__hip_bfloat16*)take((size_t)BL*CONVDIM*2);
    __hip_bfloat16* xbc     = (__hip_bfloat16*)take((size_t)BL*CONVDIM*2);
    float* dtp     = (float*)take((size_t)BL*NHEADS*4);
    float* dAcs    = (float*)take((size_t)BL*NHEADS*4);
    float* states  = (float*)take((size_t)B_N*NCHUNK*NHEADS*HEADDIM*DSTATE*4);
    ushort_t* prev_bf = (ushort_t*)take((size_t)B_N*NCHUNK*NHEADS*HEADDIM*DSTATE*2);
    ushort_t* yh   = (ushort_t*)take((size_t)BL*DINNER*2);
    ushort_t* S_T  = (ushort_t*)take((size_t)B_N*NCHUNK*CHUNK*264*2);
    ushort_t* u_bf  = (ushort_t*)take((size_t)BL*DMODEL*2);
    ushort_t* Wi_bf = (ushort_t*)take((size_t)DINPROJ*DMODEL*2);
    ushort_t* Wo_bf = (ushort_t*)take((size_t)DMODEL*DINNER*2);
    float* wT       = (float*)take((size_t)DCONV*CONVDIM*4);
    __hip_bfloat16* g = z;   // alias: z dead after gate_norm's elementwise read

    cvt_all<<<dim3((N_U8+N_WI8+N_WO8 + 255)/256), 256, 0, stream>>>(
        u, W_in, W_out, u_bf, Wi_bf, Wo_bf);
    cvt_wT<<<dim3((CONVDIM+255)/256), 256, 0, stream>>>(conv_w, wT);

    // in-proj: proven 2-phase 128^2 (64 x 35 = 2240 wg)
    gemm_bt_mfma<DMODEL,35,1><<<dim3(64*35), 256, 0, stream>>>(
        u_bf, Wi_bf, nullptr, (ushort_t*)z, (ushort_t*)xbc_raw, dt_bias, dtp);

    conv_silu<<<dim3((BL/2)*(CONVDIM/8)/256), 256, 0, stream>>>(xbc_raw, wT, conv_b, xbc);
    dt_cumsum<<<dim3(B_N*NHEADS*NCHUNK), 256, 0, stream>>>(dtp, A_log, dAcs);
    bc_scores_mfma<<<dim3(B_N*NCHUNK), 256, 0, stream>>>(xbc, S_T);
    ssd_states_mfma<<<dim3(B_N*NCHUNK, NHEADS/4), 256, 0, stream>>>(xbc, dtp, dAcs, states);
    scan_states<<<dim3((B_N*NHEADS*HEADDIM*DSTATE)/256), 256, 0, stream>>>(states, dAcs, prev_bf);
    ssd_mfma<<<dim3(B_N*NCHUNK, NHEADS), 256, 0, stream>>>(xbc, dtp, dAcs, prev_bf, S_T, D_param, yh);
    gate_norm<<<dim3(BL), 256, 0, stream>>>(yh, z, norm_w, g);

    // out-proj: proven 2-phase 128^2 (64 x 8 = 512 wg)
    gemm_bt_mfma<DINNER,8,0><<<dim3(64*8), 256, 0, stream>>>(
        (const ushort_t*)g, Wo_bf, out, nullptr, nullptr, nullptr, nullptr);
}

// Round 15
// 348.206 us; speedup vs baseline: 1.1572x; 1.0124x over previous
//
#include <hip/hip_runtime.h>
#include <hip/hip_bf16.h>
#include <math.h>

#define B_N     4
#define L_N     2048
#define DMODEL  1024
#define DSTATE  128
#define DCONV   4
#define HEADDIM 64
#define CHUNK   256
#define DINNER  2048
#define NHEADS  32
#define CONVDIM 2304
#define DINPROJ 4384
#define NCHUNK  8
#define BL      (B_N*L_N)

typedef unsigned short ushort_t;
typedef unsigned int   uint_t;

typedef __attribute__((ext_vector_type(8))) short bf16x8;
typedef __attribute__((ext_vector_type(4))) float f32x4;

__device__ __forceinline__ float bfbits2f(ushort_t u){
    union { uint_t i; float f; } v; v.i = ((uint_t)u) << 16; return v.f;
}
__device__ __forceinline__ ushort_t f2bf(float f){
    union { float f; uint_t i; } v; v.f = f;
    uint_t r = v.i + 0x7FFF + ((v.i >> 16) & 1);
    return (ushort_t)(r >> 16);
}
__device__ __forceinline__ void gload_lds16(const void* g, void* l){
    __builtin_amdgcn_global_load_lds(
        (const __attribute__((address_space(1))) unsigned int*)g,
        (__attribute__((address_space(3))) unsigned int*)l, 16, 0, 0);
}

// ---------------------------------------------------------------------------
// K0: fused f32 -> bf16 convert for u / W_in / W_out (8 elems/thread)
// ---------------------------------------------------------------------------
#define N_U8  (BL*DMODEL/8)
#define N_WI8 (DINPROJ*DMODEL/8)
#define N_WO8 (DMODEL*DINNER/8)

__global__ __launch_bounds__(256) void cvt_all(
    const float* __restrict__ u, const float* __restrict__ W_in,
    const float* __restrict__ W_out,
    ushort_t* __restrict__ u_bf, ushort_t* __restrict__ Wi_bf,
    ushort_t* __restrict__ Wo_bf)
{
    int i = blockIdx.x*256 + threadIdx.x;
    const float* src; ushort_t* dst; int off;
    if (i < N_U8)                { src = u;     dst = u_bf;  off = i; }
    else if (i < N_U8+N_WI8)     { src = W_in;  dst = Wi_bf; off = i - N_U8; }
    else if (i < N_U8+N_WI8+N_WO8){ src = W_out; dst = Wo_bf; off = i - N_U8 - N_WI8; }
    else return;
    const float4* p = (const float4*)(src + (size_t)off*8);
    float4 a = p[0], b = p[1];
    ushort_t o[8] = { f2bf(a.x), f2bf(a.y), f2bf(a.z), f2bf(a.w),
                      f2bf(b.x), f2bf(b.y), f2bf(b.z), f2bf(b.w) };
    *(uint4*)(dst + (size_t)off*8) = *(const uint4*)o;
}

// ---------------------------------------------------------------------------
// K0b: transpose conv weights: wT[k][c] = cw[c][k]
// ---------------------------------------------------------------------------
__global__ __launch_bounds__(256) void cvt_wT(
    const float* __restrict__ cw, float* __restrict__ wT)
{
    int c = blockIdx.x*256 + threadIdx.x;
    if (c >= CONVDIM) return;
    float4 v = *(const float4*)&cw[c*DCONV];
    wT[0*CONVDIM + c] = v.x;
    wT[1*CONVDIM + c] = v.y;
    wT[2*CONVDIM + c] = v.z;
    wT[3*CONVDIM + c] = v.w;
}

// ---------------------------------------------------------------------------
// K1: bf16 MFMA GEMM, C = A @ B^T. 128x128 tile, BK=32, 4 waves. (frozen)
// ---------------------------------------------------------------------------
template<int KDIM, int NTILES, int EPI>
__global__ __launch_bounds__(256) void gemm_bt_mfma(
    const ushort_t* __restrict__ A, const ushort_t* __restrict__ B,
    float* __restrict__ outf, ushort_t* __restrict__ z, ushort_t* __restrict__ xbc,
    const float* __restrict__ dt_bias, float* __restrict__ dtp)
{
    __shared__ __align__(16) ushort_t Asl[2][128*32];
    __shared__ __align__(16) ushort_t Bsl[2][128*32];

    int nwg = gridDim.x, cpx = nwg >> 3, lin = blockIdx.x;
    int work = (lin & 7)*cpx + (lin >> 3);
    int mtile = work / NTILES, ntile = work % NTILES;
    int m0 = mtile*128, n0 = ntile*128;

    int t = threadIdx.x;
    int l = t & 63, w = t >> 6;
    int wr = w >> 1, wc = w & 1;
    int lr16 = l & 15, kb = l >> 4;
    int srow = t >> 2, skc = (t & 3)*8;

    f32x4 acc[4][4];
    #pragma unroll
    for (int m=0;m<4;m++){
        #pragma unroll
        for (int n=0;n<4;n++) acc[m][n] = (f32x4){0.f,0.f,0.f,0.f};
    }

    int br0 = n0 + srow, br1 = n0 + 64 + srow;
    if (EPI == 1){
        br0 = (br0 < DINPROJ) ? br0 : (DINPROJ-1);
        br1 = (br1 < DINPROJ) ? br1 : (DINPROJ-1);
    }

    auto stage = [&](int buf, int k0){
        gload_lds16(A + (size_t)(m0+srow)*KDIM + k0 + skc,    &Asl[buf][t*8]);
        gload_lds16(A + (size_t)(m0+64+srow)*KDIM + k0 + skc, &Asl[buf][2048 + t*8]);
        gload_lds16(B + (size_t)br0*KDIM + k0 + skc,          &Bsl[buf][t*8]);
        gload_lds16(B + (size_t)br1*KDIM + k0 + skc,          &Bsl[buf][2048 + t*8]);
    };

    auto compute = [&](int cur){
        bf16x8 af[4], bfr[4];
        #pragma unroll
        for (int m=0;m<4;m++) af[m]  = *(const bf16x8*)&Asl[cur][(wr*64+m*16+lr16)*32 + kb*8];
        #pragma unroll
        for (int n=0;n<4;n++) bfr[n] = *(const bf16x8*)&Bsl[cur][(wc*64+n*16+lr16)*32 + kb*8];
        __builtin_amdgcn_s_setprio(1);
        #pragma unroll
        for (int m=0;m<4;m++){
            #pragma unroll
            for (int n=0;n<4;n++)
                acc[m][n] = __builtin_amdgcn_mfma_f32_16x16x32_bf16(af[m], bfr[n], acc[m][n], 0, 0, 0);
        }
        __builtin_amdgcn_s_setprio(0);
    };

    stage(0, 0);
    __syncthreads();
    int cur = 0;
    for (int k0=32; k0<KDIM; k0+=32){
        stage(cur^1, k0);
        compute(cur);
        __syncthreads();
        cur ^= 1;
    }
    compute(cur);

    #pragma unroll
    for (int m=0;m<4;m++){
        int rbase = m0 + wr*64 + m*16 + (l>>4)*4;
        #pragma unroll
        for (int n=0;n<4;n++){
            int gcol = n0 + wc*64 + n*16 + lr16;
            f32x4 v = acc[m][n];
            #pragma unroll
            for (int q=0;q<4;q++){
                int row = rbase + q;
                if (EPI == 0) {
                    outf[(size_t)row*DMODEL + gcol] = v[q];
                } else {
                    if (gcol < DINNER) {
                        z[(size_t)row*DINNER + gcol] = f2bf(v[q]);
                    } else if (gcol < DINNER + CONVDIM) {
                        xbc[(size_t)row*CONVDIM + (gcol - DINNER)] = f2bf(v[q]);
                    } else if (gcol < DINPROJ) {
                        int hh = gcol - (DINNER + CONVDIM);
                        float x = v[q] + dt_bias[hh];
                        float sp = (x > 15.f) ? x : log1pf(__expf(x));
                        int bb = row >> 11, ll = row & (L_N-1);
                        dtp[((size_t)bb*NHEADS + hh)*L_N + ll] = sp;
                    }
                }
            }
        }
    }
}

// ---------------------------------------------------------------------------
// K2: causal depthwise conv1d + bias + SiLU — 2 tokens x 8 channels / thread
// ---------------------------------------------------------------------------
__global__ __launch_bounds__(256) void conv_silu(
    const __hip_bfloat16* __restrict__ xraw,
    const float* __restrict__ wT, const float* __restrict__ cb,
    __hip_bfloat16* __restrict__ xout)
{
    int idx = blockIdx.x*256 + threadIdx.x;       // (BL/2) * (CONVDIM/8)
    int c8 = (idx % (CONVDIM/8))*8;
    int ml = idx / (CONVDIM/8);
    int b  = ml / (L_N/2);
    int l  = (ml % (L_N/2))*2;
    const ushort_t* xr = (const ushort_t*)xraw;

    float wv[4][8];
    #pragma unroll
    for (int k=0;k<DCONV;k++){
        float4 w0 = *(const float4*)&wT[k*CONVDIM + c8];
        float4 w1 = *(const float4*)&wT[k*CONVDIM + c8 + 4];
        wv[k][0]=w0.x; wv[k][1]=w0.y; wv[k][2]=w0.z; wv[k][3]=w0.w;
        wv[k][4]=w1.x; wv[k][5]=w1.y; wv[k][6]=w1.z; wv[k][7]=w1.w;
    }
    float bias[8];
    {
        float4 b0 = *(const float4*)&cb[c8];
        float4 b1 = *(const float4*)&cb[c8+4];
        bias[0]=b0.x; bias[1]=b0.y; bias[2]=b0.z; bias[3]=b0.w;
        bias[4]=b1.x; bias[5]=b1.y; bias[6]=b1.z; bias[7]=b1.w;
    }

    float xv[5][8];
    #pragma unroll
    for (int r=0;r<5;r++){
        int li = l - 3 + r;
        if (li >= 0){
            bf16x8 v = *(const bf16x8*)&xr[((size_t)b*L_N + li)*CONVDIM + c8];
            #pragma unroll
            for (int e=0;e<8;e++) xv[r][e] = bfbits2f(((const ushort_t*)&v)[e]);
        } else {
            #pragma unroll
            for (int e=0;e<8;e++) xv[r][e] = 0.f;
        }
    }

    ushort_t o0[8], o1[8];
    #pragma unroll
    for (int e=0;e<8;e++){
        float a0 = bias[e], a1 = bias[e];
        #pragma unroll
        for (int k=0;k<DCONV;k++){
            a0 += wv[k][e]*xv[k][e];
            a1 += wv[k][e]*xv[k+1][e];
        }
        o0[e] = f2bf(a0 / (1.f + __expf(-a0)));
        o1[e] = f2bf(a1 / (1.f + __expf(-a1)));
    }
    ushort_t* ob = (ushort_t*)xout + ((size_t)b*L_N + l)*CONVDIM + c8;
    *(uint4*)ob = *(const uint4*)o0;
    *(uint4*)(ob + CONVDIM) = *(const uint4*)o1;
}

// ---------------------------------------------------------------------------
// K3: dA = dt*A; inclusive cumsum within each chunk
// ---------------------------------------------------------------------------
__global__ __launch_bounds__(256) void dt_cumsum(
    const float* __restrict__ dtp, const float* __restrict__ A_log,
    float* __restrict__ dAcs)
{
    int blk = blockIdx.x;
    int c  = blk % NCHUNK;
    int bh = blk / NCHUNK;
    int h  = bh & (NHEADS-1);
    int t  = threadIdx.x;
    float A = -__expf(A_log[h]);
    __shared__ float sm[CHUNK];
    float v = dtp[(size_t)bh*L_N + c*CHUNK + t] * A;
    sm[t] = v;
    __syncthreads();
    for (int off=1; off<CHUNK; off<<=1){
        float add = (t >= off) ? sm[t-off] : 0.f;
        __syncthreads();
        sm[t] += add;
        __syncthreads();
    }
    dAcs[(size_t)bh*L_N + c*CHUNK + t] = sm[t];
}

// ---------------------------------------------------------------------------
// K4: S_T[bc][j][i] = sum_n B[j,n]*C[i,n]  (bf16). Split per i-block:
// grid (bc, if4). Block stages B full + C strip; wave w does j-block w<=if4.
// ---------------------------------------------------------------------------
__global__ __launch_bounds__(256) void bc_scores_mfma(
    const __hip_bfloat16* __restrict__ xbc, ushort_t* __restrict__ S_T)
{
    __shared__ __align__(16) ushort_t Bs2[256*136];   // 68 KB
    __shared__ __align__(16) ushort_t Cs2[64*136];    // 17 KB
    int bc = blockIdx.x, if4 = blockIdx.y;
    int t = threadIdx.x;
    int l = t & 63, w = t >> 6;
    int l15 = l & 15, l4 = l >> 4;
    const ushort_t* xb = (const ushort_t*)xbc;
    const size_t rowbase = (size_t)bc*CHUNK*CONVDIM;

    #pragma unroll
    for (int ps=0; ps<16; ps++){
        int idx = ps*256 + t;
        int r = idx >> 4, ck = idx & 15;
        *(uint4*)&Bs2[r*136 + ck*8] =
            *(const uint4*)&xb[rowbase + (size_t)r*CONVDIM + DINNER + ck*8];
    }
    #pragma unroll
    for (int ps=0; ps<4; ps++){
        int idx = ps*256 + t;
        int r = idx >> 4, ck = idx & 15;
        *(uint4*)&Cs2[r*136 + ck*8] =
            *(const uint4*)&xb[rowbase + (size_t)(if4*64 + r)*CONVDIM + (DINNER+DSTATE) + ck*8];
    }
    __syncthreads();

    if (w > if4) return;    // wave-uniform

    f32x4 acc[4][4];
    #pragma unroll
    for (int jf=0;jf<4;jf++){
        #pragma unroll
        for (int ir=0;ir<4;ir++) acc[jf][ir] = (f32x4){0.f,0.f,0.f,0.f};
    }
    #pragma unroll
    for (int k=0;k<4;k++){
        bf16x8 af[4], bfC[4];
        #pragma unroll
        for (int jf=0;jf<4;jf++)
            af[jf] = *(const bf16x8*)&Bs2[(w*64 + jf*16 + l15)*136 + k*32 + l4*8];
        #pragma unroll
        for (int ir=0;ir<4;ir++)
            bfC[ir] = *(const bf16x8*)&Cs2[(ir*16 + l15)*136 + k*32 + l4*8];
        #pragma unroll
        for (int jf=0;jf<4;jf++){
            #pragma unroll
            for (int ir=0;ir<4;ir++)
                acc[jf][ir] = __builtin_amdgcn_mfma_f32_16x16x32_bf16(af[jf], bfC[ir], acc[jf][ir], 0, 0, 0);
        }
    }
    ushort_t* Sb = S_T + (size_t)bc*CHUNK*264;
    #pragma unroll
    for (int jf=0;jf<4;jf++){
        #pragma unroll
        for (int ir=0;ir<4;ir++){
            #pragma unroll
            for (int q=0;q<4;q++){
                int j = w*64 + jf*16 + l4*4 + q;
                int i = if4*64 + ir*16 + l15;
                Sb[(size_t)j*264 + i] = f2bf(acc[jf][ir][q]);
            }
        }
    }
}

// ---------------------------------------------------------------------------
// K6: states via MFMA; n-dim split across 2 blocks (LDS 69 KB -> 2 blocks/CU)
// grid (bc, hg*2+nh): hg = y>>1 head group of 4, nh = y&1 n-half.
// ---------------------------------------------------------------------------
__device__ __forceinline__ int swz264(int row, int col){
    return row*264 + (col ^ (((row>>3)&7)<<3));
}

__global__ __launch_bounds__(256) void ssd_states_mfma(
    const __hip_bfloat16* __restrict__ xbc,
    const float* __restrict__ dtp, const float* __restrict__ dAcs,
    float* __restrict__ states)
{
    __shared__ __align__(16) ushort_t xdT[64*264];    // 33.8 KB
    __shared__ __align__(16) ushort_t BTh[64*264];    // 33.8 KB (n-half)
    __shared__ float coef_s[CHUNK];
    int bc = blockIdx.x;
    int hg = blockIdx.y >> 1, nh = blockIdx.y & 1;
    int b = bc >> 3, c = bc & 7;
    int t = threadIdx.x;
    int l = t & 63, w = t >> 6;
    int l15 = l & 15, l4 = l >> 4;
    const ushort_t* xb = (const ushort_t*)xbc;
    const size_t rowbase = (size_t)bc*CHUNK*CONVDIM;

    // stage BTh[nl][j] = B[j][nh*64 + nl]  (swizzled)
    #pragma unroll
    for (int ps=0; ps<8; ps++){
        int idx = ps*256 + t;
        int j = idx >> 3, n0 = (idx & 7)*8;
        bf16x8 v = *(const bf16x8*)&xb[rowbase + (size_t)j*CONVDIM + DINNER + nh*64 + n0];
        #pragma unroll
        for (int e=0;e<8;e++)
            BTh[swz264(n0+e, j)] = ((const ushort_t*)&v)[e];
    }

    for (int hh=0; hh<4; hh++){
        int h = hg*4 + hh;
        size_t dbase = ((size_t)b*NHEADS + h)*L_N + c*CHUNK;
        float last = dAcs[dbase + CHUNK-1];
        float cf = __expf(last - dAcs[dbase + t]) * dtp[dbase + t];
        coef_s[t] = cf;
        __syncthreads();   // coef ready; prev-iter xdT readers done; BTh ready (iter 0)

        #pragma unroll
        for (int ps=0; ps<8; ps++){
            int idx = ps*256 + t;
            int j = idx >> 3, p0 = (idx & 7)*8;
            float cj = coef_s[j];
            bf16x8 v = *(const bf16x8*)&xb[rowbase + (size_t)j*CONVDIM + h*HEADDIM + p0];
            #pragma unroll
            for (int e=0;e<8;e++)
                xdT[swz264(p0+e, j)] = f2bf(cj * bfbits2f(((const ushort_t*)&v)[e]));
        }
        __syncthreads();

        f32x4 acc[4];
        #pragma unroll
        for (int pf=0;pf<4;pf++) acc[pf] = (f32x4){0.f,0.f,0.f,0.f};

        #pragma unroll
        for (int k=0;k<8;k++){
            bf16x8 af[4];
            #pragma unroll
            for (int pf=0;pf<4;pf++)
                af[pf] = *(const bf16x8*)&xdT[swz264(pf*16 + l15, k*32 + l4*8)];
            bf16x8 bv = *(const bf16x8*)&BTh[swz264(w*16 + l15, k*32 + l4*8)];
            __builtin_amdgcn_s_setprio(1);
            #pragma unroll
            for (int pf=0;pf<4;pf++)
                acc[pf] = __builtin_amdgcn_mfma_f32_16x16x32_bf16(af[pf], bv, acc[pf], 0, 0, 0);
            __builtin_amdgcn_s_setprio(0);
        }

        float* sb = states + (size_t)(bc*NHEADS + h)*HEADDIM*DSTATE;
        int n = nh*64 + w*16 + l15;
        #pragma unroll
        for (int pf=0;pf<4;pf++){
            #pragma unroll
            for (int q=0;q<4;q++){
                int p = pf*16 + l4*4 + q;
                sb[(size_t)p*DSTATE + n] = acc[pf][q];
            }
        }
    }
}

// ---------------------------------------------------------------------------
// K7: inter-chunk scan -> prev_bf (bf16)
// ---------------------------------------------------------------------------
__global__ __launch_bounds__(256) void scan_states(
    const float* __restrict__ states, const float* __restrict__ dAcs,
    ushort_t* __restrict__ prev_bf)
{
    int idx = blockIdx.x*256 + threadIdx.x;
    int n  = idx & 127;
    int p  = (idx >> 7) & 63;
    int bh = idx >> 13;
    int b  = bh >> 5, h = bh & 31;
    float carry = 0.f;
    for (int c=0;c<NCHUNK;c++){
        size_t off = (((size_t)((b*NCHUNK + c)*NHEADS + h))*HEADDIM + p)*DSTATE + n;
        prev_bf[off] = f2bf(carry);
        float s = states[off];
        float cd = __expf(dAcs[((size_t)b*NHEADS + h)*L_N + c*CHUNK + (CHUNK-1)]);
        carry = carry * cd + s;
    }
}

// ---------------------------------------------------------------------------
// K5: fused MFMA SSD -> bf16 yh
// ---------------------------------------------------------------------------
__global__ __launch_bounds__(256) void ssd_mfma(
    const __hip_bfloat16* __restrict__ xbc,
    const float* __restrict__ dtp, const float* __restrict__ dAcs,
    const ushort_t* __restrict__ prev_bf, const ushort_t* __restrict__ S_T,
    const float* __restrict__ D_param, ushort_t* __restrict__ yh)
{
    __shared__ __align__(16) ushort_t Ws[256*72];
    __shared__ __align__(16) ushort_t xdT[64*264];
    __shared__ float da_s[CHUNK];
    __shared__ float dt_s[CHUNK];

    int bc = blockIdx.x, h = blockIdx.y;
    int b = bc >> 3, c = bc & 7;
    int t = threadIdx.x;
    int l = t & 63, w = t >> 6;
    int l15 = l & 15, l4 = l >> 4;

    const ushort_t* xb = (const ushort_t*)xbc;
    const size_t rowbase = (size_t)bc*CHUNK*CONVDIM;

    da_s[t] = dAcs[((size_t)b*NHEADS + h)*L_N + c*CHUNK + t];
    dt_s[t] = dtp[((size_t)b*NHEADS + h)*L_N + c*CHUNK + t];

    #pragma unroll
    for (int ps=0; ps<8; ps++){
        int idx = ps*256 + t;
        int j = idx >> 3, p0 = (idx & 7)*8;
        bf16x8 v = *(const bf16x8*)&xb[rowbase + (size_t)j*CONVDIM + h*HEADDIM + p0];
        #pragma unroll
        for (int e=0;e<8;e++) xdT[(p0+e)*264 + j] = ((const ushort_t*)&v)[e];
    }
    __syncthreads();

    f32x4 yacc[4][4];
    #pragma unroll
    for (int m=0;m<4;m++){
        #pragma unroll
        for (int np=0;np<4;np++) yacc[m][np] = (f32x4){0.f,0.f,0.f,0.f};
    }

    const ushort_t* cbase = xb + rowbase + (size_t)l15*CONVDIM + (DINNER+DSTATE) + l4*8;
    const ushort_t* pbase = prev_bf + (size_t)(bc*NHEADS + h)*HEADDIM*DSTATE
                                    + (size_t)l15*DSTATE + l4*8;
    #pragma unroll
    for (int k=0;k<4;k++){
        bf16x8 bfk[4];
        #pragma unroll
        for (int np=0;np<4;np++)
            bfk[np] = *(const bf16x8*)(pbase + (size_t)(np*16)*DSTATE + k*32);
        bf16x8 af0 = *(const bf16x8*)(cbase + (size_t)((0*4+w)*16)*CONVDIM + k*32);
        bf16x8 af1 = *(const bf16x8*)(cbase + (size_t)((1*4+w)*16)*CONVDIM + k*32);
        bf16x8 af2 = *(const bf16x8*)(cbase + (size_t)((2*4+w)*16)*CONVDIM + k*32);
        bf16x8 af3 = *(const bf16x8*)(cbase + (size_t)((3*4+w)*16)*CONVDIM + k*32);
        __builtin_amdgcn_s_setprio(1);
        #pragma unroll
        for (int np=0;np<4;np++){
            yacc[0][np] = __builtin_amdgcn_mfma_f32_16x16x32_bf16(af0, bfk[np], yacc[0][np], 0, 0, 0);
            yacc[1][np] = __builtin_amdgcn_mfma_f32_16x16x32_bf16(af1, bfk[np], yacc[1][np], 0, 0, 0);
            yacc[2][np] = __builtin_amdgcn_mfma_f32_16x16x32_bf16(af2, bfk[np], yacc[2][np], 0, 0, 0);
            yacc[3][np] = __builtin_amdgcn_mfma_f32_16x16x32_bf16(af3, bfk[np], yacc[3][np], 0, 0, 0);
        }
        __builtin_amdgcn_s_setprio(0);
    }
    #pragma unroll
    for (int m=0;m<4;m++){
        int i0 = (m*4 + w)*16;
        #pragma unroll
        for (int q=0;q<4;q++){
            float e = __expf(da_s[i0 + l4*4 + q]);
            #pragma unroll
            for (int np=0;np<4;np++) yacc[m][np][q] *= e;
        }
    }

    const ushort_t* Sb = S_T + (size_t)bc*CHUNK*264;
    for (int jp=0; jp<4; jp++){
        bf16x8 bfx[4][2];
        #pragma unroll
        for (int np=0;np<4;np++){
            #pragma unroll
            for (int ks=0;ks<2;ks++)
                bfx[np][ks] = *(const bf16x8*)&xdT[(np*16 + l15)*264 + jp*64 + ks*32 + l4*8];
        }

        #pragma unroll
        for (int m=0;m<4;m++){
            int i0 = (m*4 + w)*16;
            int imax = i0 + 15;
            int kmaxY = (jp*64 <= imax ? 1 : 0) + (jp*64+32 <= imax ? 1 : 0);
            if (kmaxY == 0) continue;
            int nmax = 2*kmaxY;

            float dai[4];
            #pragma unroll
            for (int q=0;q<4;q++) dai[q] = da_s[i0 + l4*4 + q];
            #pragma unroll
            for (int n=0;n<4;n++){
                if (n < nmax){
                    int jcol = jp*64 + n*16 + l15;
                    float daj = da_s[jcol], dtj = dt_s[jcol];
                    ushort_t sv[4];
                    *(uint2*)sv = *(const uint2*)&Sb[(size_t)jcol*264 + i0 + l4*4];
                    #pragma unroll
                    for (int q=0;q<4;q++){
                        int i = i0 + l4*4 + q;
                        float wv = 0.f;
                        if (jcol <= i) wv = __expf(dai[q] - daj) * dtj * bfbits2f(sv[q]);
                        Ws[i*72 + n*16 + l15] = f2bf(wv);
                    }
                }
            }
            __builtin_amdgcn_s_setprio(1);
            #pragma unroll
            for (int ks=0;ks<2;ks++){
                if (ks < kmaxY){
                    bf16x8 wfA = *(const bf16x8*)&Ws[(i0 + l15)*72 + ks*32 + l4*8];
                    #pragma unroll
                    for (int np=0;np<4;np++)
                        yacc[m][np] = __builtin_amdgcn_mfma_f32_16x16x32_bf16(wfA, bfx[np][ks], yacc[m][np], 0, 0, 0);
                }
            }
            __builtin_amdgcn_s_setprio(0);
        }
    }

    float Dh = D_param[h];
    #pragma unroll
    for (int m=0;m<4;m++){
        int i0 = (m*4 + w)*16;
        #pragma unroll
        for (int np=0;np<4;np++){
            int p = np*16 + l15;
            #pragma unroll
            for (int q=0;q<4;q++){
                int i = i0 + l4*4 + q;
                float xv = bfbits2f(xdT[p*264 + i]);
                yh[((size_t)bc*CHUNK + i)*DINNER + h*HEADDIM + p] = f2bf(yacc[m][np][q] + Dh*xv);
            }
        }
    }
}

// ---------------------------------------------------------------------------
// K9: g = RMSNorm(yh * silu(z))*norm_w -> bf16 g
// ---------------------------------------------------------------------------
__global__ __launch_bounds__(256) void gate_norm(
    const ushort_t* __restrict__ yh, const __hip_bfloat16* __restrict__ z,
    const float* __restrict__ norm_w, __hip_bfloat16* __restrict__ g)
{
    int row = blockIdx.x;
    int t = threadIdx.x;
    const ushort_t* yr = yh + (size_t)row*DINNER + t*8;
    const ushort_t* zr = (const ushort_t*)z + (size_t)row*DINNER + t*8;
    bf16x8 yv = *(const bf16x8*)yr;
    bf16x8 zv8 = *(const bf16x8*)zr;
    float v[8];
    float ss = 0.f;
    #pragma unroll
    for (int e=0;e<8;e++){
        float y = bfbits2f(((const ushort_t*)&yv)[e]);
        float zz = bfbits2f(((const ushort_t*)&zv8)[e]);
        float gv = y * (zz / (1.f + __expf(-zz)));
        v[e] = gv; ss += gv*gv;
    }
    #pragma unroll
    for (int off=32; off>=1; off>>=1) ss += __shfl_xor(ss, off);
    __shared__ float red[4];
    if ((t & 63) == 0) red[t >> 6] = ss;
    __syncthreads();
    float tot = red[0]+red[1]+red[2]+red[3];
    float scale = rsqrtf(tot * (1.f/DINNER) + 1e-5f);
    float4 w0 = *(const float4*)&norm_w[t*8];
    float4 w1 = *(const float4*)&norm_w[t*8+4];
    float nw[8] = {w0.x,w0.y,w0.z,w0.w,w1.x,w1.y,w1.z,w1.w};
    ushort_t o[8];
    #pragma unroll
    for (int e=0;e<8;e++) o[e] = f2bf(v[e]*scale*nw[e]);
    *(uint4*)((ushort_t*)g + (size_t)row*DINNER + t*8) = *(const uint4*)o;
}

// ---------------------------------------------------------------------------
extern "C" void kernel_launch(void* const* d_in, const int* in_sizes, int n_in,
                              void* d_out, int out_size, void* d_ws, size_t ws_size,
                              hipStream_t stream)
{
    const float* u       = (const float*)d_in[0];
    const float* W_in    = (const float*)d_in[1];
    const float* conv_w  = (const float*)d_in[2];
    const float* conv_b  = (const float*)d_in[3];
    const float* dt_bias = (const float*)d_in[4];
    const float* A_log   = (const float*)d_in[5];
    const float* D_param = (const float*)d_in[6];
    const float* norm_w  = (const float*)d_in[7];
    const float* W_out   = (const float*)d_in[8];
    float* out = (float*)d_out;

    char* p = (char*)d_ws;
    auto take = [&](size_t n){ char* r = p; p += (n + 255) & ~(size_t)255; return r; };

    __hip_bfloat16* z       = (__hip_bfloat16*)take((size_t)BL*DINNER*2);
    __hip_bfloat16* xbc_raw = (__hip_bfloat16*)take((size_t)BL*CONVDIM*2);
    __hip_bfloat16* xbc     = (__hip_bfloat16*)take((size_t)BL*CONVDIM*2);
    float* dtp     = (float*)take((size_t)BL*NHEADS*4);
    float* dAcs    = (float*)take((size_t)BL*NHEADS*4);
    float* states  = (float*)take((size_t)B_N*NCHUNK*NHEADS*HEADDIM*DSTATE*4);
    ushort_t* prev_bf = (ushort_t*)take((size_t)B_N*NCHUNK*NHEADS*HEADDIM*DSTATE*2);
    ushort_t* yh   = (ushort_t*)take((size_t)BL*DINNER*2);
    ushort_t* S_T  = (ushort_t*)take((size_t)B_N*NCHUNK*CHUNK*264*2);
    ushort_t* u_bf  = (ushort_t*)take((size_t)BL*DMODEL*2);
    ushort_t* Wi_bf = (ushort_t*)take((size_t)DINPROJ*DMODEL*2);
    ushort_t* Wo_bf = (ushort_t*)take((size_t)DMODEL*DINNER*2);
    float* wT       = (float*)take((size_t)DCONV*CONVDIM*4);
    __hip_bfloat16* g = z;   // alias: z dead after gate_norm's elementwise read

    cvt_all<<<dim3((N_U8+N_WI8+N_WO8 + 255)/256), 256, 0, stream>>>(
        u, W_in, W_out, u_bf, Wi_bf, Wo_bf);
    cvt_wT<<<dim3((CONVDIM+255)/256), 256, 0, stream>>>(conv_w, wT);

    // in-proj: proven 2-phase 128^2 (64 x 35 = 2240 wg)
    gemm_bt_mfma<DMODEL,35,1><<<dim3(64*35), 256, 0, stream>>>(
        u_bf, Wi_bf, nullptr, (ushort_t*)z, (ushort_t*)xbc_raw, dt_bias, dtp);

    conv_silu<<<dim3((BL/2)*(CONVDIM/8)/256), 256, 0, stream>>>(xbc_raw, wT, conv_b, xbc);
    dt_cumsum<<<dim3(B_N*NHEADS*NCHUNK), 256, 0, stream>>>(dtp, A_log, dAcs);
    bc_scores_mfma<<<dim3(B_N*NCHUNK, 4), 256, 0, stream>>>(xbc, S_T);
    ssd_states_mfma<<<dim3(B_N*NCHUNK, 16), 256, 0, stream>>>(xbc, dtp, dAcs, states);
    scan_states<<<dim3((B_N*NHEADS*HEADDIM*DSTATE)/256), 256, 0, stream>>>(states, dAcs, prev_bf);
    ssd_mfma<<<dim3(B_N*NCHUNK, NHEADS), 256, 0, stream>>>(xbc, dtp, dAcs, prev_bf, S_T, D_param, yh);
    gate_norm<<<dim3(BL), 256, 0, stream>>>(yh, z, norm_w, g);

    // out-proj: proven 2-phase 128^2 (64 x 8 = 512 wg)
    gemm_bt_mfma<DINNER,8,0><<<dim3(64*8), 256, 0, stream>>>(
        (const ushort_t*)g, Wo_bf, out, nullptr, nullptr, nullptr, nullptr);
}